// Round 2
// baseline (306.182 us; speedup 1.0000x reference)
//
#include <hip/hip_runtime.h>

typedef _Float16 f16;
typedef __attribute__((ext_vector_type(8))) _Float16 half8;
typedef __attribute__((ext_vector_type(4))) _Float16 half4;
typedef __attribute__((ext_vector_type(4))) float f32x4;

#define DEVINL static __device__ __forceinline__

constexpr float NORMALIZER = 0.35355339059327373f;  // 64^-0.25
constexpr float RATIO      = 0.08838834764831845f;  // 1/sqrt(128)
constexpr float FEPS       = 1e-6f;

// ---------------- workspace layout (bytes) ----------------
constexpr size_t OFF_WQKVT = 0;                                   // [2304][768] f16
constexpr size_t OFF_WOT   = OFF_WQKVT + (size_t)2304*768*2;      // [768][768] f16
constexpr size_t OFF_PROJF = OFF_WOT   + (size_t)768*768*2;       // [128][64] f16 (pre-scaled)
constexpr size_t OFF_KS    = OFF_PROJF + (size_t)128*64*2;        // [48][128] f32
constexpr size_t OFF_KSP   = OFF_KS    + (size_t)48*128*4;        // [48*64][128] f32
constexpr size_t OFF_DEN   = OFF_KSP   + (size_t)48*64*128*4;     // [48][4096] f32
constexpr size_t OFF_KVST  = OFF_DEN   + (size_t)48*4096*4;       // [48][64][128] f16
constexpr size_t OFF_KVSP  = OFF_KVST  + (size_t)48*64*128*2;     // [8][48][128][64] f32
constexpr size_t OFF_X16   = OFF_KVSP  + (size_t)8*48*128*64*4;   // [16384][768] f16
constexpr size_t OFF_ATT   = OFF_X16;                              // alias (x16 dead after QKV GEMM)
constexpr size_t OFF_Q16   = OFF_X16 + (size_t)16384*768*2;
constexpr size_t OFF_K16   = OFF_Q16 + (size_t)16384*768*2;
constexpr size_t OFF_VT    = OFF_K16 + (size_t)16384*768*2;       // [48][64][4096] f16
constexpr size_t OFF_QP    = OFF_K16;                              // alias K16+VT (both dead by then)
constexpr size_t OFF_KPT   = OFF_VT  + (size_t)16384*768*2;       // [48][128][4096] f16

// ---------------- helpers ----------------
DEVINL void gload_lds16(const f16* g, f16* lds) {
  __builtin_amdgcn_global_load_lds(
      (const __attribute__((address_space(1))) void*)g,
      (__attribute__((address_space(3))) void*)lds, 16, 0, 0);
}

// =====================================================================
// 256x256 tile, BK=32, 4-buffer pipelined GEMM core (f16 in, f32 acc).
// C[256 x 256] = A[256 x 768] * Bt[256 x 768]^T   (lda = ldb = 768)
// 512 threads = 8 waves in 2(M) x 4(N); per-wave tile 128 x 64.
// LDS per buffer: A [4 g][256 row][8 f16] + B same = 32 KiB; 4 bufs = 128 KiB.
// Stage tile t+3 while computing tile t; s_waitcnt vmcnt(8) once per tile.
// WAR-safe: buffer (t+3)&3 was last read during tile t-1 (barrier-separated).
// =====================================================================
DEVINL void gemm256_core(const f16* __restrict__ Ag, const f16* __restrict__ Bg,
                         f16* smem, f32x4 (&acc)[8][4], int w, int lane)
{
  constexpr int NT = 24;                 // 768 / 32
  const int wm = w >> 2, wn = w & 3;
  const int c = lane & 15, g16 = lane >> 4;

#pragma unroll
  for (int i = 0; i < 8; ++i)
#pragma unroll
    for (int j = 0; j < 4; ++j)
      acc[i][j] = f32x4{0.f, 0.f, 0.f, 0.f};

  // -------- prologue: stage tiles 0,1,2 (12 loads/wave) --------
#pragma unroll
  for (int pt = 0; pt < 3; ++pt) {
    f16* stg = smem + pt * 16384;
#pragma unroll
    for (int u = 0; u < 2; ++u) {
      const int a = 2 * w + u, gg = a & 3, rb = (a >> 2) * 64;
      gload_lds16(Ag + (size_t)(rb + lane) * 768 + pt * 32 + gg * 8,
                  stg + gg * 2048 + rb * 8);
      gload_lds16(Bg + (size_t)(rb + lane) * 768 + pt * 32 + gg * 8,
                  stg + 8192 + gg * 2048 + rb * 8);
    }
  }
  asm volatile("s_waitcnt vmcnt(8)" ::: "memory");   // tile 0 complete
  __builtin_amdgcn_s_barrier();

  // -------- main loop --------
#pragma unroll 1
  for (int t = 0; t < NT; ++t) {
    const f16* sb = smem + (t & 3) * 16384;
    f16* stg = smem + ((t + 3) & 3) * 16384;
    const int kst = (t + 3) * 32;
    const bool do_stage = (t + 3) < NT;
    half8 av[4], bv[4];

    // ---- phase A: rows-half 0 ----
#pragma unroll
    for (int j = 0; j < 4; ++j)
      bv[j] = *(const half8*)(sb + 8192 + g16 * 2048 + (wn * 64 + j * 16 + c) * 8);
#pragma unroll
    for (int i = 0; i < 4; ++i)
      av[i] = *(const half8*)(sb + g16 * 2048 + (wm * 128 + i * 16 + c) * 8);
    if (do_stage) {
#pragma unroll
      for (int u = 0; u < 2; ++u) {
        const int a = 2 * w + u, gg = a & 3, rb = (a >> 2) * 64;
        gload_lds16(Ag + (size_t)(rb + lane) * 768 + kst + gg * 8,
                    stg + gg * 2048 + rb * 8);
      }
    }
    __builtin_amdgcn_s_barrier();
    __builtin_amdgcn_s_setprio(1);
#pragma unroll
    for (int i = 0; i < 4; ++i)
#pragma unroll
      for (int j = 0; j < 4; ++j)
        acc[i][j] = __builtin_amdgcn_mfma_f32_16x16x32_f16(av[i], bv[j], acc[i][j], 0, 0, 0);
    __builtin_amdgcn_s_setprio(0);
    __builtin_amdgcn_s_barrier();

    // ---- phase B: rows-half 1 ----
#pragma unroll
    for (int i = 0; i < 4; ++i)
      av[i] = *(const half8*)(sb + g16 * 2048 + (wm * 128 + 64 + i * 16 + c) * 8);
    if (do_stage) {
#pragma unroll
      for (int u = 0; u < 2; ++u) {
        const int a = 2 * w + u, gg = a & 3, rb = (a >> 2) * 64;
        gload_lds16(Bg + (size_t)(rb + lane) * 768 + kst + gg * 8,
                    stg + 8192 + gg * 2048 + rb * 8);
      }
    }
    __builtin_amdgcn_s_barrier();
    __builtin_amdgcn_s_setprio(1);
#pragma unroll
    for (int i = 0; i < 4; ++i)
#pragma unroll
      for (int j = 0; j < 4; ++j)
        acc[4 + i][j] = __builtin_amdgcn_mfma_f32_16x16x32_f16(av[i], bv[j], acc[4 + i][j], 0, 0, 0);
    __builtin_amdgcn_s_setprio(0);
    // counted drain: guarantee tile t+1 resident before next tile's reads
    if (t <= NT - 4)      asm volatile("s_waitcnt vmcnt(8)" ::: "memory");
    else if (t == NT - 3) asm volatile("s_waitcnt vmcnt(4)" ::: "memory");
    else if (t == NT - 2) asm volatile("s_waitcnt vmcnt(0)" ::: "memory");
    __builtin_amdgcn_s_barrier();
  }
}

// ---------------- QKV GEMM (256² core; writes Q,K normal; V transposed) ----------------
__global__ __launch_bounds__(512, 2) void k_gemm_qkv2(const f16* __restrict__ X16, const f16* __restrict__ WT,
    const float* __restrict__ bq, const float* __restrict__ bk, const float* __restrict__ bv,
    f16* __restrict__ Qo, f16* __restrict__ Ko, f16* __restrict__ VT)
{
  __shared__ f16 smem[65536];            // 128 KiB
  f32x4 acc[8][4];
  const int by = blockIdx.x;             // [0,9)
  const int bx = blockIdx.y;             // [0,64)
  const int brow0 = bx * 256;
  const int t = threadIdx.x, w = t >> 6, lane = t & 63;
  gemm256_core(X16 + (size_t)brow0 * 768, WT + (size_t)by * 256 * 768, smem, acc, w, lane);

  const int wm = w >> 2, wn = w & 3;
  const int c = lane & 15, g16 = lane >> 4;
  const int which = by / 3;              // 0:q 1:k 2:v (uniform per block)
  const int colhdr = (by % 3) * 256;     // col offset within the 768-wide output
  const float* bias = which == 0 ? bq : (which == 1 ? bk : bv);
  float bb[4];
#pragma unroll
  for (int j = 0; j < 4; ++j) bb[j] = bias[colhdr + wn * 64 + j * 16 + c];

  if (which < 2) {
    // ---- Q/K: LDS bounce -> coalesced row-major store ----
    f16* ep = smem;                      // [128][264]
    f16* QK = which == 0 ? Qo : Ko;
#pragma unroll 1
    for (int p = 0; p < 2; ++p) {
      __syncthreads();
      if (wm == p) {
#pragma unroll
        for (int i = 0; i < 8; ++i)
#pragma unroll
          for (int j = 0; j < 4; ++j)
#pragma unroll
            for (int r = 0; r < 4; ++r)
              ep[(i * 16 + g16 * 4 + r) * 264 + wn * 64 + j * 16 + c] = (f16)(acc[i][j][r] + bb[j]);
      }
      __syncthreads();
      const int row = threadIdx.x >> 2, seg = (threadIdx.x & 3) * 64;
      f16* dst = QK + (size_t)(brow0 + p * 128 + row) * 768 + colhdr + seg;
      const f16* sp = ep + row * 264 + seg;
#pragma unroll
      for (int u = 0; u < 8; ++u) *(half8*)(dst + u * 8) = *(const half8*)(sp + u * 8);
    }
  } else {
    // ---- V: transposed LDS bounce -> VT [bh][d][l] ----
    f16* ep = smem;                      // [256][136]
    const int bIdx = brow0 >> 12;
#pragma unroll 1
    for (int p = 0; p < 2; ++p) {
      __syncthreads();
      if (wm == p) {
#pragma unroll
        for (int i = 0; i < 8; ++i)
#pragma unroll
          for (int j = 0; j < 4; ++j)
#pragma unroll
            for (int r = 0; r < 4; ++r)
              ep[(wn * 64 + j * 16 + c) * 136 + i * 16 + g16 * 4 + r] = (f16)(acc[i][j][r] + bb[j]);
      }
      __syncthreads();
      const int col = threadIdx.x >> 1, seg = (threadIdx.x & 1) * 64;
      const int vcol = colhdr + col;
      const int h = vcol >> 6, d = vcol & 63;
      f16* dst = VT + ((size_t)(bIdx * 12 + h) * 64 + d) * 4096 + (brow0 & 4095) + p * 128 + seg;
      const f16* sp = ep + col * 136 + seg;
#pragma unroll
      for (int u = 0; u < 8; ++u) *(half8*)(dst + u * 8) = *(const half8*)(sp + u * 8);
    }
  }
}

// ---------------- final GEMM (256² core) ----------------
__global__ __launch_bounds__(512, 2) void k_gemm_out2(const f16* __restrict__ ATT, const f16* __restrict__ WOT,
    const float* __restrict__ bo, float* __restrict__ out)
{
  __shared__ f16 smem[65536];
  f32x4 acc[8][4];
  const int by = blockIdx.x;             // [0,3)
  const int bx = blockIdx.y;             // [0,64)
  const int brow0 = bx * 256;
  const int t = threadIdx.x, w = t >> 6, lane = t & 63;
  gemm256_core(ATT + (size_t)brow0 * 768, WOT + (size_t)by * 256 * 768, smem, acc, w, lane);

  const int wm = w >> 2, wn = w & 3;
  const int c = lane & 15, g16 = lane >> 4;
  float bb[4];
#pragma unroll
  for (int j = 0; j < 4; ++j) bb[j] = bo[by * 256 + wn * 64 + j * 16 + c];
#pragma unroll
  for (int i = 0; i < 8; ++i) {
    const int row0 = brow0 + wm * 128 + i * 16 + g16 * 4;
#pragma unroll
    for (int j = 0; j < 4; ++j) {
      const int col = by * 256 + wn * 64 + j * 16 + c;
#pragma unroll
      for (int r = 0; r < 4; ++r)
        out[(size_t)(row0 + r) * 768 + col] = acc[i][j][r] + bb[j];
    }
  }
}

// =====================================================================
// 128-tile GEMM core (round-1, kept for kvs / num kernels)
// =====================================================================
template<int BN>
DEVINL void gemm_tile(const f16* A, int lda, const f16* Bt, int ldb, int K,
                      f16* As, f16* Bs, f32x4 (&acc)[4][BN/32])
{
  constexpr int NF = BN/32;
  const int t = threadIdx.x;
  const int w = t >> 6, lane = t & 63;
  const int g = lane >> 4, c = lane & 15;
  const int wr = w >> 1, wc = w & 1;
  const int srow = lane >> 2;
  const int sseg = (lane & 3) * 8;

#pragma unroll
  for (int i = 0; i < 4; ++i)
#pragma unroll
    for (int j = 0; j < NF; ++j)
      acc[i][j] = f32x4{0.f, 0.f, 0.f, 0.f};

  for (int k0 = 0; k0 < K; k0 += 32) {
#pragma unroll
    for (int r = 0; r < 2; ++r) {                 // A: 128 rows x 64B
      const int rowblk = (w + 4*r) * 16;
      gload_lds16(A + (size_t)(rowblk + srow) * lda + k0 + sseg, As + rowblk*32);
    }
#pragma unroll
    for (int r = 0; r < BN/64; ++r) {             // B: BN rows x 64B
      const int rowblk = (w + 4*r) * 16;
      gload_lds16(Bt + (size_t)(rowblk + srow) * ldb + k0 + sseg, Bs + rowblk*32);
    }
    __syncthreads();
    half8 av[4], bv[NF];
#pragma unroll
    for (int i = 0; i < 4; ++i)
      av[i] = *(const half8*)(As + (wr*64 + i*16 + c)*32 + g*8);
#pragma unroll
    for (int j = 0; j < NF; ++j)
      bv[j] = *(const half8*)(Bs + (wc*(BN/2) + j*16 + c)*32 + g*8);
#pragma unroll
    for (int i = 0; i < 4; ++i)
#pragma unroll
      for (int j = 0; j < NF; ++j)
        acc[i][j] = __builtin_amdgcn_mfma_f32_16x16x32_f16(av[i], bv[j], acc[i][j], 0, 0, 0);
    __syncthreads();
  }
}

// ---------------- cast / transpose kernels ----------------
__global__ __launch_bounds__(256) void k_cast_x(const float* __restrict__ X, f16* __restrict__ X16)
{
  const size_t i = ((size_t)blockIdx.x*256 + threadIdx.x) * 4;
  const float4 v = *(const float4*)(X + i);
  half4 h;
  h[0] = (f16)v.x; h[1] = (f16)v.y; h[2] = (f16)v.z; h[3] = (f16)v.w;
  *(half4*)(X16 + i) = h;
}

__global__ __launch_bounds__(256) void k_transpose_w(const float* __restrict__ W, f16* __restrict__ Wt)
{
  __shared__ float ls[64][65];
  const int t = threadIdx.x;
  const int k0 = blockIdx.x*64, n0 = blockIdx.y*64;
#pragma unroll
  for (int it = 0; it < 4; ++it) {
    const int r = it*16 + (t >> 4);
    const int cs = (t & 15) * 4;
    const float4 v = *(const float4*)(W + (size_t)(k0 + r)*768 + n0 + cs);
    ls[r][cs+0] = v.x; ls[r][cs+1] = v.y; ls[r][cs+2] = v.z; ls[r][cs+3] = v.w;
  }
  __syncthreads();
  const int n = t >> 2;
  const int seg = (t & 3) * 16;
  half8 ov[2];
#pragma unroll
  for (int i = 0; i < 16; ++i) ov[i>>3][i&7] = (f16)ls[seg + i][n];
  f16* dst = Wt + (size_t)(n0 + n)*768 + k0 + seg;
  *(half8*)dst = ov[0];
  *(half8*)(dst + 8) = ov[1];
}

__global__ __launch_bounds__(256) void k_cast_proj(const float* __restrict__ P, f16* __restrict__ PF)
{
  const int i = blockIdx.x*256 + threadIdx.x;   // 8192
  PF[i] = (f16)(NORMALIZER * P[i]);
}

// ---------------- feature kernels ----------------
DEVINL void feat_common(const f16* base, const f16* PROJF,
                        f16* qs, f16* ps, float* dd, float* diag_s)
{
  const int t = threadIdx.x, w = t >> 6, lane = t & 63;
#pragma unroll
  for (int it = 0; it < 2; ++it) {
    const int rowblk = it*32 + w*8;
    gload_lds16(base + (size_t)(rowblk + (lane>>3))*768 + (lane&7)*8, qs + rowblk*64);
  }
#pragma unroll
  for (int it = 0; it < 4; ++it) {
    const int rowblk = it*32 + w*8;
    gload_lds16(PROJF + (size_t)(rowblk + (lane>>3))*64 + (lane&7)*8, ps + rowblk*64);
  }
  __syncthreads();
  if (t < 64) {
    float s = 0.f;
    for (int d = 0; d < 64; ++d) { const float qv = (float)qs[t*64 + d]; s += qv*qv; }
    diag_s[t] = 0.0625f * s;   // 0.5 * (normalizer^2) * sum q^2
  }
  const int g = lane >> 4, c = lane & 15;
  const int wr = w >> 1, wc = w & 1;
  f32x4 facc[2][4];
#pragma unroll
  for (int i = 0; i < 2; ++i)
#pragma unroll
    for (int j = 0; j < 4; ++j) facc[i][j] = f32x4{0.f,0.f,0.f,0.f};
#pragma unroll
  for (int kk = 0; kk < 2; ++kk) {
    half8 av[2], bv[4];
#pragma unroll
    for (int i = 0; i < 2; ++i) av[i] = *(const half8*)(qs + (wr*32 + i*16 + c)*64 + kk*32 + g*8);
#pragma unroll
    for (int j = 0; j < 4; ++j) bv[j] = *(const half8*)(ps + (wc*64 + j*16 + c)*64 + kk*32 + g*8);
#pragma unroll
    for (int i = 0; i < 2; ++i)
#pragma unroll
      for (int j = 0; j < 4; ++j)
        facc[i][j] = __builtin_amdgcn_mfma_f32_16x16x32_f16(av[i], bv[j], facc[i][j], 0, 0, 0);
  }
#pragma unroll
  for (int i = 0; i < 2; ++i)
#pragma unroll
    for (int j = 0; j < 4; ++j)
#pragma unroll
      for (int r = 0; r < 4; ++r)
        dd[(wr*32 + i*16 + g*4 + r)*129 + wc*64 + j*16 + c] = facc[i][j][r];
  __syncthreads();
}

__global__ __launch_bounds__(256) void k_qfeat(const f16* __restrict__ Q, const f16* __restrict__ PROJF,
    const float* __restrict__ KS, f16* __restrict__ QP, float* __restrict__ DEN)
{
  __shared__ f16 qs[64*64];
  __shared__ f16 ps[128*64];
  __shared__ float dd[64*129];
  __shared__ float diag_s[64];
  __shared__ float ks_s[128];
  const int t = threadIdx.x;
  const int lb = blockIdx.x, bh = blockIdx.y;
  const int b = bh / 12, h = bh - b*12;
  if (t < 128) ks_s[t] = KS[bh*128 + t];
  feat_common(Q + ((size_t)(b*4096 + lb*64))*768 + h*64, PROJF, qs, ps, dd, diag_s);
  const int l = t >> 2, s = t & 3;
  float v[32];
#pragma unroll
  for (int j = 0; j < 32; ++j) v[j] = dd[l*129 + s*32 + j];
  float mx = v[0];
#pragma unroll
  for (int j = 1; j < 32; ++j) mx = fmaxf(mx, v[j]);
  mx = fmaxf(mx, __shfl_xor(mx, 1));
  mx = fmaxf(mx, __shfl_xor(mx, 2));
  const float off = diag_s[l] + mx;
  half8 ov[4];
  float dp = 0.f;
#pragma unroll
  for (int j = 0; j < 32; ++j) {
    const float e = RATIO * (__expf(v[j] - off) + FEPS);
    ov[j>>3][j&7] = (f16)e;
    dp += e * ks_s[s*32 + j];
  }
  dp += __shfl_xor(dp, 1);
  dp += __shfl_xor(dp, 2);
  const size_t lrow = (size_t)bh*4096 + lb*64 + l;
  if (s == 0) DEN[lrow] = dp;
  f16* dst = QP + lrow*128 + s*32;
#pragma unroll
  for (int q8 = 0; q8 < 4; ++q8) *(half8*)(dst + q8*8) = ov[q8];
}

__global__ __launch_bounds__(256) void k_kfeat(const f16* __restrict__ Kin, const f16* __restrict__ PROJF,
    f16* __restrict__ KPT, float* __restrict__ KSP)
{
  __shared__ f16 qs[64*64];
  __shared__ f16 ps[128*64];
  __shared__ float dd[64*129];
  __shared__ float diag_s[64];
  const int t = threadIdx.x;
  const int lb = blockIdx.x, bh = blockIdx.y;
  const int b = bh / 12, h = bh - b*12;
  feat_common(Kin + ((size_t)(b*4096 + lb*64))*768 + h*64, PROJF, qs, ps, dd, diag_s);
  const int l = t >> 2, s = t & 3;
  float v[32];
#pragma unroll
  for (int j = 0; j < 32; ++j) v[j] = dd[l*129 + s*32 + j];
  float mx = v[0];
#pragma unroll
  for (int j = 1; j < 32; ++j) mx = fmaxf(mx, v[j]);
  mx = fmaxf(mx, __shfl_xor(mx, 1));
  mx = fmaxf(mx, __shfl_xor(mx, 2));
  const float off = diag_s[l] + mx;
#pragma unroll
  for (int j = 0; j < 32; ++j) dd[l*129 + s*32 + j] = RATIO * (__expf(v[j] - off) + FEPS);
  __syncthreads();
  if (t < 128) {
    float sm = 0.f;
    for (int l2 = 0; l2 < 64; ++l2) sm += dd[l2*129 + t];
    KSP[((size_t)bh*64 + lb)*128 + t] = sm;
  }
  const int m = t >> 1, hf = t & 1;
  half8 ov[4];
#pragma unroll
  for (int i2 = 0; i2 < 32; ++i2) ov[i2>>3][i2&7] = (f16)dd[(hf*32 + i2)*129 + m];
  f16* dst = KPT + ((size_t)bh*128 + m)*4096 + lb*64 + hf*32;
#pragma unroll
  for (int q8 = 0; q8 < 4; ++q8) *(half8*)(dst + q8*8) = ov[q8];
}

// ---------------- kvs: [48] (128m x 64d) = k'^T @ v, chunked over L ----------------
__global__ __launch_bounds__(256) void k_kvs(const f16* __restrict__ KPT, const f16* __restrict__ VT,
    float* __restrict__ KVSP)
{
  __shared__ f16 As[128*32], Bs[64*32];
  f32x4 acc[4][2];
  const int chunk = blockIdx.x, bh = blockIdx.y;   // (8, 48)
  gemm_tile<64>(KPT + (size_t)bh*128*4096 + chunk*512, 4096,
                VT  + (size_t)bh*64*4096  + chunk*512, 4096, 512, As, Bs, acc);
  const int t = threadIdx.x, w = t>>6, lane = t&63, g = lane>>4, c = lane&15;
  const int wr = w>>1, wc = w&1;
  float* dst = KVSP + (size_t)(chunk*48 + bh)*128*64;
#pragma unroll
  for (int i = 0; i < 4; ++i) {
    const int row0 = wr*64 + i*16 + g*4;
#pragma unroll
    for (int j = 0; j < 2; ++j) {
      const int col = wc*32 + j*16 + c;
#pragma unroll
      for (int r = 0; r < 4; ++r) dst[(size_t)(row0 + r)*64 + col] = acc[i][j][r];
    }
  }
}

__global__ __launch_bounds__(256) void k_reduce(const float* __restrict__ KVSP, const float* __restrict__ KSP,
    f16* __restrict__ KVST, float* __restrict__ KS)
{
  const int i = blockIdx.x*256 + threadIdx.x;
  if (i < 48*128*64) {
    const int bh = i >> 13, md = i & 8191, m = md >> 6, d = md & 63;
    float s = 0.f;
#pragma unroll
    for (int c = 0; c < 8; ++c) s += KVSP[((size_t)(c*48 + bh)*128 + m)*64 + d];
    KVST[((size_t)bh*64 + d)*128 + m] = (f16)s;
  }
  if (i < 48*128) {
    const int bh = i >> 7, m = i & 127;
    float s = 0.f;
#pragma unroll 8
    for (int lb = 0; lb < 64; ++lb) s += KSP[((size_t)bh*64 + lb)*128 + m];
    KS[i] = s;
  }
}

// ---------------- num GEMM + normalize -> ATT [bh][l][d] f16 ----------------
__global__ __launch_bounds__(256) void k_num(const f16* __restrict__ QP, const f16* __restrict__ KVST,
    const float* __restrict__ DEN, f16* __restrict__ ATT)
{
  __shared__ f16 As[128*32], Bs[64*32];
  f32x4 acc[4][2];
  const int bx = blockIdx.x, bh = blockIdx.y;      // (32, 48)
  gemm_tile<64>(QP + ((size_t)bh*4096 + bx*128)*128, 128,
                KVST + (size_t)bh*64*128, 128, 128, As, Bs, acc);
  const int t = threadIdx.x, w = t>>6, lane = t&63, g = lane>>4, c = lane&15;
  const int wr = w>>1, wc = w&1;
#pragma unroll
  for (int i = 0; i < 4; ++i) {
    const int l0 = bx*128 + wr*64 + i*16 + g*4;
#pragma unroll
    for (int j = 0; j < 2; ++j) {
      const int d = wc*32 + j*16 + c;
#pragma unroll
      for (int r = 0; r < 4; ++r) {
        const float den = DEN[(size_t)bh*4096 + l0 + r];
        ATT[((size_t)bh*4096 + l0 + r)*64 + d] = (f16)(acc[i][j][r] / den);
      }
    }
  }
}

// ---------------- launcher ----------------
extern "C" void kernel_launch(void* const* d_in, const int* in_sizes, int n_in,
                              void* d_out, int out_size, void* d_ws, size_t ws_size,
                              hipStream_t stream)
{
  const float* x    = (const float*)d_in[0];
  const float* Wq   = (const float*)d_in[1];
  const float* bq   = (const float*)d_in[2];
  const float* Wk   = (const float*)d_in[3];
  const float* bk   = (const float*)d_in[4];
  const float* Wv   = (const float*)d_in[5];
  const float* bv   = (const float*)d_in[6];
  const float* Wo   = (const float*)d_in[7];
  const float* bo   = (const float*)d_in[8];
  const float* proj = (const float*)d_in[9];
  float* out = (float*)d_out;
  char* ws = (char*)d_ws;

  f16*   WQKVT = (f16*)(ws + OFF_WQKVT);
  f16*   WOT   = (f16*)(ws + OFF_WOT);
  f16*   PROJF = (f16*)(ws + OFF_PROJF);
  float* KS    = (float*)(ws + OFF_KS);
  float* KSP   = (float*)(ws + OFF_KSP);
  float* DEN   = (float*)(ws + OFF_DEN);
  f16*   KVST  = (f16*)(ws + OFF_KVST);
  float* KVSP  = (float*)(ws + OFF_KVSP);
  f16*   X16   = (f16*)(ws + OFF_X16);
  f16*   ATT   = (f16*)(ws + OFF_ATT);
  f16*   Q16   = (f16*)(ws + OFF_Q16);
  f16*   K16   = (f16*)(ws + OFF_K16);
  f16*   VT    = (f16*)(ws + OFF_VT);
  f16*   QP    = (f16*)(ws + OFF_QP);
  f16*   KPT   = (f16*)(ws + OFF_KPT);

  k_cast_x<<<12288, 256, 0, stream>>>(x, X16);
  k_transpose_w<<<dim3(12,12), 256, 0, stream>>>(Wq, WQKVT);
  k_transpose_w<<<dim3(12,12), 256, 0, stream>>>(Wk, WQKVT + (size_t)768*768);
  k_transpose_w<<<dim3(12,12), 256, 0, stream>>>(Wv, WQKVT + (size_t)2*768*768);
  k_transpose_w<<<dim3(12,12), 256, 0, stream>>>(Wo, WOT);
  k_cast_proj<<<32, 256, 0, stream>>>(proj, PROJF);

  k_gemm_qkv2<<<dim3(9,64), 512, 0, stream>>>(X16, WQKVT, bq, bk, bv, Q16, K16, VT);
  k_kfeat<<<dim3(64,48), 256, 0, stream>>>(K16, PROJF, KPT, KSP);
  k_kvs<<<dim3(8,48), 256, 0, stream>>>(KPT, VT, KVSP);
  k_reduce<<<1536, 256, 0, stream>>>(KVSP, KSP, KVST, KS);
  k_qfeat<<<dim3(64,48), 256, 0, stream>>>(Q16, PROJF, KS, QP, DEN);
  k_num<<<dim3(32,48), 256, 0, stream>>>(QP, KVST, DEN, ATT);
  k_gemm_out2<<<dim3(3,64), 512, 0, stream>>>(ATT, WOT, bo, out);
}

// Round 3
// 290.464 us; speedup vs baseline: 1.0541x; 1.0541x over previous
//
#include <hip/hip_runtime.h>

typedef _Float16 f16;
typedef __attribute__((ext_vector_type(8))) _Float16 half8;
typedef __attribute__((ext_vector_type(4))) _Float16 half4;
typedef __attribute__((ext_vector_type(4))) float f32x4;

#define DEVINL static __device__ __forceinline__

constexpr float NORMALIZER = 0.35355339059327373f;  // 64^-0.25
constexpr float RATIO      = 0.08838834764831845f;  // 1/sqrt(128)
constexpr float FEPS       = 1e-6f;

// ---------------- workspace layout (bytes) ----------------
constexpr size_t OFF_WQKVT = 0;                                   // [2304][768] f16
constexpr size_t OFF_WOT   = OFF_WQKVT + (size_t)2304*768*2;      // [768][768] f16
constexpr size_t OFF_PROJF = OFF_WOT   + (size_t)768*768*2;       // [128][64] f16 (pre-scaled)
constexpr size_t OFF_KS    = OFF_PROJF + (size_t)128*64*2;        // [48][128] f32
constexpr size_t OFF_KSP   = OFF_KS    + (size_t)48*128*4;        // [48*64][128] f32
constexpr size_t OFF_DEN   = OFF_KSP   + (size_t)48*64*128*4;     // [48][4096] f32
constexpr size_t OFF_KVST  = OFF_DEN   + (size_t)48*4096*4;       // [48][64][128] f16
constexpr size_t OFF_KVSP  = OFF_KVST  + (size_t)48*64*128*2;     // [8][48][128][64] f32
constexpr size_t OFF_X16   = OFF_KVSP  + (size_t)8*48*128*64*4;   // [16384][768] f16
constexpr size_t OFF_ATT   = OFF_X16;                              // alias (x16 dead after QKV GEMM)
constexpr size_t OFF_Q16   = OFF_X16 + (size_t)16384*768*2;
constexpr size_t OFF_K16   = OFF_Q16 + (size_t)16384*768*2;
constexpr size_t OFF_VT    = OFF_K16 + (size_t)16384*768*2;       // [48][64][4096] f16
constexpr size_t OFF_QP    = OFF_K16;                              // alias K16+VT (both dead by then)
constexpr size_t OFF_KPT   = OFF_VT  + (size_t)16384*768*2;       // [48][128][4096] f16

// ---------------- helpers ----------------
DEVINL void gload_lds16(const f16* g, f16* lds) {
  __builtin_amdgcn_global_load_lds(
      (const __attribute__((address_space(1))) void*)g,
      (__attribute__((address_space(3))) void*)lds, 16, 0, 0);
}

// =====================================================================
// 256x128 tile, BK=64, 3-buffer pipelined GEMM core (f16 in, f32 acc).
// C[256 x 128] = A[256 x 768] * Bt[128 x 768]^T   (lda = ldb = 768)
// 512 threads = 8 waves in 4(M) x 2(N); per-wave tile 64 x 64 (acc 4x4).
// LDS buffer: A [256 r][64 k] row-major swizzled (32 KiB) + B [128][64]
// (16 KiB) = 48 KiB; 3 buffers = 144 KiB.
// XOR swizzle: 16B-seg' = seg ^ (row&7)  (both on stage-source and ds_read)
//  -> global side: each 8-lane group reads one contiguous 128B row segment
//  -> LDS side: 16 lanes of a frag-read spread over 8 bank-quads (2-way, free)
// Pipeline: stage tile t+2 while computing tile t; s_waitcnt vmcnt(6)/tile.
// =====================================================================
DEVINL void mfma16(const half8 (&av)[4], const half8 (&bv)[4], f32x4 (&acc)[4][4]) {
  __builtin_amdgcn_s_setprio(1);
#pragma unroll
  for (int i = 0; i < 4; ++i)
#pragma unroll
    for (int j = 0; j < 4; ++j)
      acc[i][j] = __builtin_amdgcn_mfma_f32_16x16x32_f16(av[i], bv[j], acc[i][j], 0, 0, 0);
  __builtin_amdgcn_s_setprio(0);
}

DEVINL void gemm_mt_core(const f16* __restrict__ Ag, const f16* __restrict__ Bg,
                         f16* smem, f32x4 (&acc)[4][4], int w, int lane)
{
  constexpr int NT = 12;                 // 768 / 64
  const int wm = w >> 1, wn = w & 1;
  const int c = lane & 15, g16 = lane >> 4;
  const int lr = lane >> 3;              // 0..7 : row within 8-row stage block
  const int gseg = (lane & 7) ^ lr;      // permuted global 16B segment

#pragma unroll
  for (int i = 0; i < 4; ++i)
#pragma unroll
    for (int j = 0; j < 4; ++j)
      acc[i][j] = f32x4{0.f, 0.f, 0.f, 0.f};

  auto stageA = [&](int tt, f16* buf) {
#pragma unroll
    for (int u = 0; u < 4; ++u) {
      const int R = (w * 4 + u) * 8;     // 32 blocks x 8 rows = 256 rows
      gload_lds16(Ag + (size_t)(R + lr) * 768 + tt * 64 + gseg * 8, buf + R * 64);
    }
  };
  auto stageB = [&](int tt, f16* buf) {
#pragma unroll
    for (int u = 0; u < 2; ++u) {
      const int R = (w * 2 + u) * 8;     // 16 blocks x 8 rows = 128 rows
      gload_lds16(Bg + (size_t)(R + lr) * 768 + tt * 64 + gseg * 8, buf + 16384 + R * 64);
    }
  };
  auto rdA = [&](const f16* buf, int kk, half8 (&av)[4]) {
#pragma unroll
    for (int i = 0; i < 4; ++i) {
      const int r = wm * 64 + i * 16 + c;
      av[i] = *(const half8*)(buf + r * 64 + (((kk << 2) | g16) ^ (r & 7)) * 8);
    }
  };
  auto rdB = [&](const f16* buf, int kk, half8 (&bv)[4]) {
#pragma unroll
    for (int j = 0; j < 4; ++j) {
      const int r = wn * 64 + j * 16 + c;
      bv[j] = *(const half8*)(buf + 16384 + r * 64 + (((kk << 2) | g16) ^ (r & 7)) * 8);
    }
  };

  // -------- prologue: stage tiles 0,1 --------
  stageA(0, smem);          stageB(0, smem);
  stageA(1, smem + 24576);  stageB(1, smem + 24576);
  asm volatile("s_waitcnt vmcnt(6)" ::: "memory");   // tile 0 complete (own 6)
  __builtin_amdgcn_s_barrier();
  __builtin_amdgcn_sched_barrier(0);

  int sel = 0;
#pragma unroll 1
  for (int t = 0; t < NT; ++t) {
    const f16* bufR = smem + sel * 24576;
    int selW = sel + 2; if (selW >= 3) selW -= 3;
    f16* bufW = smem + selW * 24576;
    const bool st = (t + 2) < NT;
    half8 av[4], bv[4];

    // ---- phase kk=0 ----
    rdA(bufR, 0, av); rdB(bufR, 0, bv);
    if (st) stageA(t + 2, bufW);
    mfma16(av, bv, acc);

    // ---- phase kk=1 ----
    rdA(bufR, 1, av); rdB(bufR, 1, bv);
    if (st) stageB(t + 2, bufW);
    mfma16(av, bv, acc);

    // tile boundary: own next-tile loads resident; keep t+2's 6 in flight
    if (t < NT - 2) asm volatile("s_waitcnt vmcnt(6)" ::: "memory");
    else            asm volatile("s_waitcnt vmcnt(0)" ::: "memory");
    __builtin_amdgcn_s_barrier();
    __builtin_amdgcn_sched_barrier(0);
    sel = sel + 1; if (sel >= 3) sel -= 3;
  }
}

// ---------------- QKV GEMM (writes Q,K normal; V transposed) ----------------
__global__ __launch_bounds__(512, 2) void k_gemm_qkv3(const f16* __restrict__ X16, const f16* __restrict__ WT,
    const float* __restrict__ bq, const float* __restrict__ bk, const float* __restrict__ bv,
    f16* __restrict__ Qo, f16* __restrict__ Ko, f16* __restrict__ VT)
{
  __shared__ f16 smem[73728];            // 144 KiB
  f32x4 acc[4][4];
  const int by = blockIdx.x;             // [0,18) : N tile (128 wide)
  const int bx = blockIdx.y;             // [0,64) : M tile (256 rows)
  const int brow0 = bx * 256;
  const int t = threadIdx.x, w = t >> 6, lane = t & 63;
  gemm_mt_core(X16 + (size_t)brow0 * 768, WT + (size_t)by * 128 * 768, smem, acc, w, lane);

  const int wm = w >> 1, wn = w & 1;
  const int c = lane & 15, g16 = lane >> 4;
  const int which = by / 6;              // 0:q 1:k 2:v (uniform per block)
  const int colhdr = (by % 6) * 128;     // col offset within the 768-wide output
  const float* bias = which == 0 ? bq : (which == 1 ? bk : bv);
  float bb[4];
#pragma unroll
  for (int j = 0; j < 4; ++j) bb[j] = bias[colhdr + wn * 64 + j * 16 + c];

  __syncthreads();                       // core done; smem reusable
  if (which < 2) {
    // ---- Q/K: LDS bounce [256][136] -> coalesced row-major store ----
    f16* ep = smem;
#pragma unroll
    for (int i = 0; i < 4; ++i)
#pragma unroll
      for (int j = 0; j < 4; ++j)
#pragma unroll
        for (int r = 0; r < 4; ++r)
          ep[(wm * 64 + i * 16 + g16 * 4 + r) * 136 + wn * 64 + j * 16 + c] = (f16)(acc[i][j][r] + bb[j]);
    __syncthreads();
    f16* QK = which == 0 ? Qo : Ko;
    const int tr = threadIdx.x >> 1, hf = threadIdx.x & 1;
    f16* dst = QK + (size_t)(brow0 + tr) * 768 + colhdr + hf * 64;
    const f16* sp = ep + tr * 136 + hf * 64;
#pragma unroll
    for (int u = 0; u < 8; ++u) *(half8*)(dst + u * 8) = *(const half8*)(sp + u * 8);
  } else {
    // ---- V: transposed LDS bounce [128 col][264] -> VT [bh][d][l] ----
    f16* ep = smem;
#pragma unroll
    for (int i = 0; i < 4; ++i)
#pragma unroll
      for (int j = 0; j < 4; ++j)
#pragma unroll
        for (int r = 0; r < 4; ++r)
          ep[(wn * 64 + j * 16 + c) * 264 + wm * 64 + i * 16 + g16 * 4 + r] = (f16)(acc[i][j][r] + bb[j]);
    __syncthreads();
    const int cl = threadIdx.x >> 2, seg = (threadIdx.x & 3) * 64;
    const int vcol = colhdr + cl;
    const int h = vcol >> 6, d = vcol & 63;
    f16* dst = VT + ((size_t)((brow0 >> 12) * 12 + h) * 64 + d) * 4096 + (brow0 & 4095) + seg;
    const f16* sp = ep + cl * 264 + seg;
#pragma unroll
    for (int u = 0; u < 8; ++u) *(half8*)(dst + u * 8) = *(const half8*)(sp + u * 8);
  }
}

// ---------------- final GEMM ----------------
__global__ __launch_bounds__(512, 2) void k_gemm_out3(const f16* __restrict__ ATT, const f16* __restrict__ WOT,
    const float* __restrict__ bo, float* __restrict__ out)
{
  __shared__ f16 smem[73728];
  f32x4 acc[4][4];
  const int by = blockIdx.x;             // [0,6)
  const int bx = blockIdx.y;             // [0,64)
  const int brow0 = bx * 256;
  const int t = threadIdx.x, w = t >> 6, lane = t & 63;
  gemm_mt_core(ATT + (size_t)brow0 * 768, WOT + (size_t)by * 128 * 768, smem, acc, w, lane);

  const int wm = w >> 1, wn = w & 1;
  const int c = lane & 15, g16 = lane >> 4;
  float bb[4];
#pragma unroll
  for (int j = 0; j < 4; ++j) bb[j] = bo[by * 128 + wn * 64 + j * 16 + c];
#pragma unroll
  for (int i = 0; i < 4; ++i) {
    const int row0 = brow0 + wm * 64 + i * 16 + g16 * 4;
#pragma unroll
    for (int j = 0; j < 4; ++j) {
      const int col = by * 128 + wn * 64 + j * 16 + c;
#pragma unroll
      for (int r = 0; r < 4; ++r)
        out[(size_t)(row0 + r) * 768 + col] = acc[i][j][r] + bb[j];
    }
  }
}

// =====================================================================
// 128-tile GEMM core (round-1, kept for kvs / num kernels)
// =====================================================================
template<int BN>
DEVINL void gemm_tile(const f16* A, int lda, const f16* Bt, int ldb, int K,
                      f16* As, f16* Bs, f32x4 (&acc)[4][BN/32])
{
  constexpr int NF = BN/32;
  const int t = threadIdx.x;
  const int w = t >> 6, lane = t & 63;
  const int g = lane >> 4, c = lane & 15;
  const int wr = w >> 1, wc = w & 1;
  const int srow = lane >> 2;
  const int sseg = (lane & 3) * 8;

#pragma unroll
  for (int i = 0; i < 4; ++i)
#pragma unroll
    for (int j = 0; j < NF; ++j)
      acc[i][j] = f32x4{0.f, 0.f, 0.f, 0.f};

  for (int k0 = 0; k0 < K; k0 += 32) {
#pragma unroll
    for (int r = 0; r < 2; ++r) {                 // A: 128 rows x 64B
      const int rowblk = (w + 4*r) * 16;
      gload_lds16(A + (size_t)(rowblk + srow) * lda + k0 + sseg, As + rowblk*32);
    }
#pragma unroll
    for (int r = 0; r < BN/64; ++r) {             // B: BN rows x 64B
      const int rowblk = (w + 4*r) * 16;
      gload_lds16(Bt + (size_t)(rowblk + srow) * ldb + k0 + sseg, Bs + rowblk*32);
    }
    __syncthreads();
    half8 av[4], bv[NF];
#pragma unroll
    for (int i = 0; i < 4; ++i)
      av[i] = *(const half8*)(As + (wr*64 + i*16 + c)*32 + g*8);
#pragma unroll
    for (int j = 0; j < NF; ++j)
      bv[j] = *(const half8*)(Bs + (wc*(BN/2) + j*16 + c)*32 + g*8);
#pragma unroll
    for (int i = 0; i < 4; ++i)
#pragma unroll
      for (int j = 0; j < NF; ++j)
        acc[i][j] = __builtin_amdgcn_mfma_f32_16x16x32_f16(av[i], bv[j], acc[i][j], 0, 0, 0);
    __syncthreads();
  }
}

// ---------------- cast / transpose kernels ----------------
__global__ __launch_bounds__(256) void k_cast_x(const float* __restrict__ X, f16* __restrict__ X16)
{
  const size_t i = ((size_t)blockIdx.x*256 + threadIdx.x) * 4;
  const float4 v = *(const float4*)(X + i);
  half4 h;
  h[0] = (f16)v.x; h[1] = (f16)v.y; h[2] = (f16)v.z; h[3] = (f16)v.w;
  *(half4*)(X16 + i) = h;
}

__global__ __launch_bounds__(256) void k_transpose_w(const float* __restrict__ W, f16* __restrict__ Wt)
{
  __shared__ float ls[64][65];
  const int t = threadIdx.x;
  const int k0 = blockIdx.x*64, n0 = blockIdx.y*64;
#pragma unroll
  for (int it = 0; it < 4; ++it) {
    const int r = it*16 + (t >> 4);
    const int cs = (t & 15) * 4;
    const float4 v = *(const float4*)(W + (size_t)(k0 + r)*768 + n0 + cs);
    ls[r][cs+0] = v.x; ls[r][cs+1] = v.y; ls[r][cs+2] = v.z; ls[r][cs+3] = v.w;
  }
  __syncthreads();
  const int n = t >> 2;
  const int seg = (t & 3) * 16;
  half8 ov[2];
#pragma unroll
  for (int i = 0; i < 16; ++i) ov[i>>3][i&7] = (f16)ls[seg + i][n];
  f16* dst = Wt + (size_t)(n0 + n)*768 + k0 + seg;
  *(half8*)dst = ov[0];
  *(half8*)(dst + 8) = ov[1];
}

__global__ __launch_bounds__(256) void k_cast_proj(const float* __restrict__ P, f16* __restrict__ PF)
{
  const int i = blockIdx.x*256 + threadIdx.x;   // 8192
  PF[i] = (f16)(NORMALIZER * P[i]);
}

// ---------------- feature kernels ----------------
DEVINL void feat_common(const f16* base, const f16* PROJF,
                        f16* qs, f16* ps, float* dd, float* diag_s)
{
  const int t = threadIdx.x, w = t >> 6, lane = t & 63;
#pragma unroll
  for (int it = 0; it < 2; ++it) {
    const int rowblk = it*32 + w*8;
    gload_lds16(base + (size_t)(rowblk + (lane>>3))*768 + (lane&7)*8, qs + rowblk*64);
  }
#pragma unroll
  for (int it = 0; it < 4; ++it) {
    const int rowblk = it*32 + w*8;
    gload_lds16(PROJF + (size_t)(rowblk + (lane>>3))*64 + (lane&7)*8, ps + rowblk*64);
  }
  __syncthreads();
  if (t < 64) {
    float s = 0.f;
    for (int d = 0; d < 64; ++d) { const float qv = (float)qs[t*64 + d]; s += qv*qv; }
    diag_s[t] = 0.0625f * s;   // 0.5 * (normalizer^2) * sum q^2
  }
  const int g = lane >> 4, c = lane & 15;
  const int wr = w >> 1, wc = w & 1;
  f32x4 facc[2][4];
#pragma unroll
  for (int i = 0; i < 2; ++i)
#pragma unroll
    for (int j = 0; j < 4; ++j) facc[i][j] = f32x4{0.f,0.f,0.f,0.f};
#pragma unroll
  for (int kk = 0; kk < 2; ++kk) {
    half8 av[2], bv[4];
#pragma unroll
    for (int i = 0; i < 2; ++i) av[i] = *(const half8*)(qs + (wr*32 + i*16 + c)*64 + kk*32 + g*8);
#pragma unroll
    for (int j = 0; j < 4; ++j) bv[j] = *(const half8*)(ps + (wc*64 + j*16 + c)*64 + kk*32 + g*8);
#pragma unroll
    for (int i = 0; i < 2; ++i)
#pragma unroll
      for (int j = 0; j < 4; ++j)
        facc[i][j] = __builtin_amdgcn_mfma_f32_16x16x32_f16(av[i], bv[j], facc[i][j], 0, 0, 0);
  }
#pragma unroll
  for (int i = 0; i < 2; ++i)
#pragma unroll
    for (int j = 0; j < 4; ++j)
#pragma unroll
      for (int r = 0; r < 4; ++r)
        dd[(wr*32 + i*16 + g*4 + r)*129 + wc*64 + j*16 + c] = facc[i][j][r];
  __syncthreads();
}

__global__ __launch_bounds__(256) void k_qfeat(const f16* __restrict__ Q, const f16* __restrict__ PROJF,
    const float* __restrict__ KS, f16* __restrict__ QP, float* __restrict__ DEN)
{
  __shared__ f16 qs[64*64];
  __shared__ f16 ps[128*64];
  __shared__ float dd[64*129];
  __shared__ float diag_s[64];
  __shared__ float ks_s[128];
  const int t = threadIdx.x;
  const int lb = blockIdx.x, bh = blockIdx.y;
  const int b = bh / 12, h = bh - b*12;
  if (t < 128) ks_s[t] = KS[bh*128 + t];
  feat_common(Q + ((size_t)(b*4096 + lb*64))*768 + h*64, PROJF, qs, ps, dd, diag_s);
  const int l = t >> 2, s = t & 3;
  float v[32];
#pragma unroll
  for (int j = 0; j < 32; ++j) v[j] = dd[l*129 + s*32 + j];
  float mx = v[0];
#pragma unroll
  for (int j = 1; j < 32; ++j) mx = fmaxf(mx, v[j]);
  mx = fmaxf(mx, __shfl_xor(mx, 1));
  mx = fmaxf(mx, __shfl_xor(mx, 2));
  const float off = diag_s[l] + mx;
  half8 ov[4];
  float dp = 0.f;
#pragma unroll
  for (int j = 0; j < 32; ++j) {
    const float e = RATIO * (__expf(v[j] - off) + FEPS);
    ov[j>>3][j&7] = (f16)e;
    dp += e * ks_s[s*32 + j];
  }
  dp += __shfl_xor(dp, 1);
  dp += __shfl_xor(dp, 2);
  const size_t lrow = (size_t)bh*4096 + lb*64 + l;
  if (s == 0) DEN[lrow] = dp;
  f16* dst = QP + lrow*128 + s*32;
#pragma unroll
  for (int q8 = 0; q8 < 4; ++q8) *(half8*)(dst + q8*8) = ov[q8];
}

__global__ __launch_bounds__(256) void k_kfeat(const f16* __restrict__ Kin, const f16* __restrict__ PROJF,
    f16* __restrict__ KPT, float* __restrict__ KSP)
{
  __shared__ f16 qs[64*64];
  __shared__ f16 ps[128*64];
  __shared__ float dd[64*129];
  __shared__ float diag_s[64];
  const int t = threadIdx.x;
  const int lb = blockIdx.x, bh = blockIdx.y;
  const int b = bh / 12, h = bh - b*12;
  feat_common(Kin + ((size_t)(b*4096 + lb*64))*768 + h*64, PROJF, qs, ps, dd, diag_s);
  const int l = t >> 2, s = t & 3;
  float v[32];
#pragma unroll
  for (int j = 0; j < 32; ++j) v[j] = dd[l*129 + s*32 + j];
  float mx = v[0];
#pragma unroll
  for (int j = 1; j < 32; ++j) mx = fmaxf(mx, v[j]);
  mx = fmaxf(mx, __shfl_xor(mx, 1));
  mx = fmaxf(mx, __shfl_xor(mx, 2));
  const float off = diag_s[l] + mx;
#pragma unroll
  for (int j = 0; j < 32; ++j) dd[l*129 + s*32 + j] = RATIO * (__expf(v[j] - off) + FEPS);
  __syncthreads();
  if (t < 128) {
    float sm = 0.f;
    for (int l2 = 0; l2 < 64; ++l2) sm += dd[l2*129 + t];
    KSP[((size_t)bh*64 + lb)*128 + t] = sm;
  }
  const int m = t >> 1, hf = t & 1;
  half8 ov[4];
#pragma unroll
  for (int i2 = 0; i2 < 32; ++i2) ov[i2>>3][i2&7] = (f16)dd[(hf*32 + i2)*129 + m];
  f16* dst = KPT + ((size_t)bh*128 + m)*4096 + lb*64 + hf*32;
#pragma unroll
  for (int q8 = 0; q8 < 4; ++q8) *(half8*)(dst + q8*8) = ov[q8];
}

// ---------------- kvs: [48] (128m x 64d) = k'^T @ v, chunked over L ----------------
__global__ __launch_bounds__(256) void k_kvs(const f16* __restrict__ KPT, const f16* __restrict__ VT,
    float* __restrict__ KVSP)
{
  __shared__ f16 As[128*32], Bs[64*32];
  f32x4 acc[4][2];
  const int chunk = blockIdx.x, bh = blockIdx.y;   // (8, 48)
  gemm_tile<64>(KPT + (size_t)bh*128*4096 + chunk*512, 4096,
                VT  + (size_t)bh*64*4096  + chunk*512, 4096, 512, As, Bs, acc);
  const int t = threadIdx.x, w = t>>6, lane = t&63, g = lane>>4, c = lane&15;
  const int wr = w>>1, wc = w&1;
  float* dst = KVSP + (size_t)(chunk*48 + bh)*128*64;
#pragma unroll
  for (int i = 0; i < 4; ++i) {
    const int row0 = wr*64 + i*16 + g*4;
#pragma unroll
    for (int j = 0; j < 2; ++j) {
      const int col = wc*32 + j*16 + c;
#pragma unroll
      for (int r = 0; r < 4; ++r) dst[(size_t)(row0 + r)*64 + col] = acc[i][j][r];
    }
  }
}

__global__ __launch_bounds__(256) void k_reduce(const float* __restrict__ KVSP, const float* __restrict__ KSP,
    f16* __restrict__ KVST, float* __restrict__ KS)
{
  const int i = blockIdx.x*256 + threadIdx.x;
  if (i < 48*128*64) {
    const int bh = i >> 13, md = i & 8191, m = md >> 6, d = md & 63;
    float s = 0.f;
#pragma unroll
    for (int c = 0; c < 8; ++c) s += KVSP[((size_t)(c*48 + bh)*128 + m)*64 + d];
    KVST[((size_t)bh*64 + d)*128 + m] = (f16)s;
  }
  if (i < 48*128) {
    const int bh = i >> 7, m = i & 127;
    float s = 0.f;
#pragma unroll 8
    for (int lb = 0; lb < 64; ++lb) s += KSP[((size_t)bh*64 + lb)*128 + m];
    KS[i] = s;
  }
}

// ---------------- num GEMM + normalize -> ATT [bh][l][d] f16 ----------------
__global__ __launch_bounds__(256) void k_num(const f16* __restrict__ QP, const f16* __restrict__ KVST,
    const float* __restrict__ DEN, f16* __restrict__ ATT)
{
  __shared__ f16 As[128*32], Bs[64*32];
  f32x4 acc[4][2];
  const int bx = blockIdx.x, bh = blockIdx.y;      // (32, 48)
  gemm_tile<64>(QP + ((size_t)bh*4096 + bx*128)*128, 128,
                KVST + (size_t)bh*64*128, 128, 128, As, Bs, acc);
  const int t = threadIdx.x, w = t>>6, lane = t&63, g = lane>>4, c = lane&15;
  const int wr = w>>1, wc = w&1;
#pragma unroll
  for (int i = 0; i < 4; ++i) {
    const int l0 = bx*128 + wr*64 + i*16 + g*4;
#pragma unroll
    for (int j = 0; j < 2; ++j) {
      const int d = wc*32 + j*16 + c;
#pragma unroll
      for (int r = 0; r < 4; ++r) {
        const float den = DEN[(size_t)bh*4096 + l0 + r];
        ATT[((size_t)bh*4096 + l0 + r)*64 + d] = (f16)(acc[i][j][r] / den);
      }
    }
  }
}

// ---------------- launcher ----------------
extern "C" void kernel_launch(void* const* d_in, const int* in_sizes, int n_in,
                              void* d_out, int out_size, void* d_ws, size_t ws_size,
                              hipStream_t stream)
{
  const float* x    = (const float*)d_in[0];
  const float* Wq   = (const float*)d_in[1];
  const float* bq   = (const float*)d_in[2];
  const float* Wk   = (const float*)d_in[3];
  const float* bk   = (const float*)d_in[4];
  const float* Wv   = (const float*)d_in[5];
  const float* bv   = (const float*)d_in[6];
  const float* Wo   = (const float*)d_in[7];
  const float* bo   = (const float*)d_in[8];
  const float* proj = (const float*)d_in[9];
  float* out = (float*)d_out;
  char* ws = (char*)d_ws;

  f16*   WQKVT = (f16*)(ws + OFF_WQKVT);
  f16*   WOT   = (f16*)(ws + OFF_WOT);
  f16*   PROJF = (f16*)(ws + OFF_PROJF);
  float* KS    = (float*)(ws + OFF_KS);
  float* KSP   = (float*)(ws + OFF_KSP);
  float* DEN   = (float*)(ws + OFF_DEN);
  f16*   KVST  = (f16*)(ws + OFF_KVST);
  float* KVSP  = (float*)(ws + OFF_KVSP);
  f16*   X16   = (f16*)(ws + OFF_X16);
  f16*   ATT   = (f16*)(ws + OFF_ATT);
  f16*   Q16   = (f16*)(ws + OFF_Q16);
  f16*   K16   = (f16*)(ws + OFF_K16);
  f16*   VT    = (f16*)(ws + OFF_VT);
  f16*   QP    = (f16*)(ws + OFF_QP);
  f16*   KPT   = (f16*)(ws + OFF_KPT);

  k_cast_x<<<12288, 256, 0, stream>>>(x, X16);
  k_transpose_w<<<dim3(12,12), 256, 0, stream>>>(Wq, WQKVT);
  k_transpose_w<<<dim3(12,12), 256, 0, stream>>>(Wk, WQKVT + (size_t)768*768);
  k_transpose_w<<<dim3(12,12), 256, 0, stream>>>(Wv, WQKVT + (size_t)2*768*768);
  k_transpose_w<<<dim3(12,12), 256, 0, stream>>>(Wo, WOT);
  k_cast_proj<<<32, 256, 0, stream>>>(proj, PROJF);

  k_gemm_qkv3<<<dim3(18,64), 512, 0, stream>>>(X16, WQKVT, bq, bk, bv, Q16, K16, VT);
  k_kfeat<<<dim3(64,48), 256, 0, stream>>>(K16, PROJF, KPT, KSP);
  k_kvs<<<dim3(8,48), 256, 0, stream>>>(KPT, VT, KVSP);
  k_reduce<<<1536, 256, 0, stream>>>(KVSP, KSP, KVST, KS);
  k_qfeat<<<dim3(64,48), 256, 0, stream>>>(Q16, PROJF, KS, QP, DEN);
  k_num<<<dim3(32,48), 256, 0, stream>>>(QP, KVST, DEN, ATT);
  k_gemm_out3<<<dim3(6,64), 512, 0, stream>>>(ATT, WOT, bo, out);
}

// Round 4
// 283.473 us; speedup vs baseline: 1.0801x; 1.0247x over previous
//
#include <hip/hip_runtime.h>

typedef _Float16 f16;
typedef __attribute__((ext_vector_type(8))) _Float16 half8;
typedef __attribute__((ext_vector_type(4))) _Float16 half4;
typedef __attribute__((ext_vector_type(4))) float f32x4;

#define DEVINL static __device__ __forceinline__

constexpr float NORMALIZER = 0.35355339059327373f;  // 64^-0.25
constexpr float RATIO      = 0.08838834764831845f;  // 1/sqrt(128)
constexpr float FEPS       = 1e-6f;

// ---------------- workspace layout (bytes) ----------------
constexpr size_t OFF_WQKVT = 0;                                   // [2304][768] f16
constexpr size_t OFF_WOT   = OFF_WQKVT + (size_t)2304*768*2;      // [768][768] f16
constexpr size_t OFF_PROJF = OFF_WOT   + (size_t)768*768*2;       // [128][64] f16 (pre-scaled)
constexpr size_t OFF_KS    = OFF_PROJF + (size_t)128*64*2;        // [48][128] f32
constexpr size_t OFF_KSP   = OFF_KS    + (size_t)48*128*4;        // [48*64][128] f32
constexpr size_t OFF_DEN   = OFF_KSP   + (size_t)48*64*128*4;     // [48][4096] f32
constexpr size_t OFF_KVST  = OFF_DEN   + (size_t)48*4096*4;       // [48][64][128] f16
constexpr size_t OFF_KVSP  = OFF_KVST  + (size_t)48*64*128*2;     // [8][48][128][64] f32
constexpr size_t OFF_X16   = OFF_KVSP  + (size_t)8*48*128*64*4;   // [16384][768] f16
constexpr size_t OFF_ATT   = OFF_X16;                              // alias (x16 dead after QKV GEMM)
constexpr size_t OFF_Q16   = OFF_X16 + (size_t)16384*768*2;
constexpr size_t OFF_K16   = OFF_Q16 + (size_t)16384*768*2;
constexpr size_t OFF_VT    = OFF_K16 + (size_t)16384*768*2;       // [48][64][4096] f16
constexpr size_t OFF_QP    = OFF_K16;                              // alias K16+VT (both dead by then)
constexpr size_t OFF_KPT   = OFF_VT  + (size_t)16384*768*2;       // [48][128][4096] f16

// ---------------- helpers ----------------
DEVINL void gload_lds16(const f16* g, f16* lds) {
  __builtin_amdgcn_global_load_lds(
      (const __attribute__((address_space(1))) void*)g,
      (__attribute__((address_space(3))) void*)lds, 16, 0, 0);
}

#define VMCNT(n)  asm volatile("s_waitcnt vmcnt(" #n ")" ::: "memory")
#define LGKMCNT0  asm volatile("s_waitcnt lgkmcnt(0)" ::: "memory")
#define SCHEDB    __builtin_amdgcn_sched_barrier(0)
#define BAR       __builtin_amdgcn_s_barrier()

// =====================================================================
// 8-phase 256x256 GEMM core (T2+T3+T4+T5), f16 in / f32 acc.
// C[256x256] = A[256x768] * Bt[256x768]^T  (lda=ldb=768, K=768)
// 512 thr = 8 waves (2M x 4N); per-wave tile 128x64 -> acc[8][4].
// LDS: 2 dbuf x (A[2 khalf][256 r][32 k] + B same) = 128 KiB.
// Swizzle (both sides): 16B-seg' = seg ^ ((r ^ (r>>2)) & 3).
// Phases per K-tile (BK=64): P1{rdA(k0,m0)+rdB(k0) | stage Ak0(t+1)},
// P2{rdA(k0,m1) | stage Bk0(t+1)}, P3{rdA(k1,m0)+rdB(k1) | stage Ak1(t+1)},
// P4{rdA(k1,m1) | stage Bk1(t+1)}. vmcnt(4) at end of P2 and P4 only.
// =====================================================================
DEVINL void gemm8p_core(const f16* __restrict__ Ag, const f16* __restrict__ Bg,
                        f16* smem, f32x4 (&acc)[8][4], int w, int lane)
{
  constexpr int NT = 12;                 // 768 / 64
  const int wm = w >> 2, wn = w & 3;
  const int c = lane & 15, g16 = lane >> 4;

#pragma unroll
  for (int i = 0; i < 8; ++i)
#pragma unroll
    for (int j = 0; j < 4; ++j)
      acc[i][j] = f32x4{0.f, 0.f, 0.f, 0.f};

  auto STG = [&](const f16* g, int koff, f16* ldsbase) {
#pragma unroll
    for (int u = 0; u < 2; ++u) {
      const int r = w * 32 + u * 16 + (lane >> 2);
      const int sg = lane & 3;
      gload_lds16(g + (size_t)r * 768 + koff + ((sg ^ ((r ^ (r >> 2)) & 3)) << 3),
                  ldsbase + (w * 128 + u * 64) * 8);
    }
  };
  auto RDA = [&](const f16* kbase, int mh, half8 (&av)[4]) {
#pragma unroll
    for (int i = 0; i < 4; ++i) {
      const int r = wm * 128 + mh * 64 + i * 16 + c;
      av[i] = *(const half8*)(kbase + r * 32 + ((g16 ^ ((r ^ (r >> 2)) & 3)) << 3));
    }
  };
  auto RDB = [&](const f16* kbase, half8 (&bv)[4]) {
#pragma unroll
    for (int j = 0; j < 4; ++j) {
      const int col = wn * 64 + j * 16 + c;
      bv[j] = *(const half8*)(kbase + 16384 + col * 32 + ((g16 ^ ((col ^ (col >> 2)) & 3)) << 3));
    }
  };
  auto MF0 = [&](const half8 (&av)[4], const half8 (&bv)[4]) {
    __builtin_amdgcn_s_setprio(1);
#pragma unroll
    for (int i = 0; i < 4; ++i)
#pragma unroll
      for (int j = 0; j < 4; ++j)
        acc[i][j] = __builtin_amdgcn_mfma_f32_16x16x32_f16(av[i], bv[j], acc[i][j], 0, 0, 0);
    __builtin_amdgcn_s_setprio(0);
  };
  auto MF1 = [&](const half8 (&av)[4], const half8 (&bv)[4]) {
    __builtin_amdgcn_s_setprio(1);
#pragma unroll
    for (int i = 0; i < 4; ++i)
#pragma unroll
      for (int j = 0; j < 4; ++j)
        acc[4 + i][j] = __builtin_amdgcn_mfma_f32_16x16x32_f16(av[i], bv[j], acc[4 + i][j], 0, 0, 0);
    __builtin_amdgcn_s_setprio(0);
  };

  // -------- prologue: stage all 4 k-halves of tile 0 into buf0 --------
  STG(Ag, 0, smem);
  STG(Bg, 0, smem + 16384);
  STG(Ag, 32, smem + 8192);
  STG(Bg, 32, smem + 16384 + 8192);
  VMCNT(0);
  BAR; SCHEDB;

#pragma unroll 1
  for (int t = 0; t < NT; ++t) {
    f16* bufR = smem + (t & 1) * 32768;
    f16* bufW = smem + ((t & 1) ^ 1) * 32768;
    const int kn = (t + 1) * 64;
    const bool st = (t + 1) < NT;
    half8 av[4], bv[4];

    // ---- P1 ----
    RDA(bufR, 0, av); RDB(bufR, bv);
    if (st) STG(Ag, kn, bufW);
    SCHEDB; BAR; LGKMCNT0; SCHEDB;
    MF0(av, bv);
    BAR; SCHEDB;
    // ---- P2 ----
    RDA(bufR, 1, av);
    if (st) STG(Bg, kn, bufW + 16384);
    SCHEDB; BAR; LGKMCNT0; SCHEDB;
    MF1(av, bv);
    if (st) { VMCNT(4); } else { VMCNT(0); }
    BAR; SCHEDB;
    // ---- P3 ----
    RDA(bufR + 8192, 0, av); RDB(bufR + 8192, bv);
    if (st) STG(Ag, kn + 32, bufW + 8192);
    SCHEDB; BAR; LGKMCNT0; SCHEDB;
    MF0(av, bv);
    BAR; SCHEDB;
    // ---- P4 ----
    RDA(bufR + 8192, 1, av);
    if (st) STG(Bg, kn + 32, bufW + 16384 + 8192);
    SCHEDB; BAR; LGKMCNT0; SCHEDB;
    MF1(av, bv);
    if (st) { VMCNT(4); }
    BAR; SCHEDB;
  }
}

// ---------------- QKV GEMM (writes Q,K normal; V transposed) ----------------
__global__ __launch_bounds__(512, 2) void k_gemm_qkv4(const f16* __restrict__ X16, const f16* __restrict__ WT,
    const float* __restrict__ bq, const float* __restrict__ bk, const float* __restrict__ bv,
    f16* __restrict__ Qo, f16* __restrict__ Ko, f16* __restrict__ VT)
{
  __shared__ f16 smem[65536];            // 128 KiB
  f32x4 acc[8][4];
  // bijective XCD swizzle: 576 = 8 xcd * (8 bx * 9 by)
  const int lin = blockIdx.x;
  const int xcd = lin & 7, idx = lin >> 3;
  const int bx = xcd * 8 + idx / 9;      // [0,64)
  const int by = idx % 9;                // [0,9)
  const int brow0 = bx * 256;
  const int t = threadIdx.x, w = t >> 6, lane = t & 63;
  gemm8p_core(X16 + (size_t)brow0 * 768, WT + (size_t)by * 256 * 768, smem, acc, w, lane);

  const int wm = w >> 2, wn = w & 3;
  const int c = lane & 15, g16 = lane >> 4;
  const int which = by / 3;              // 0:q 1:k 2:v (uniform per block)
  const int colhdr = (by % 3) * 256;
  const float* bias = which == 0 ? bq : (which == 1 ? bk : bv);
  float bb[4];
#pragma unroll
  for (int j = 0; j < 4; ++j) bb[j] = bias[colhdr + wn * 64 + j * 16 + c];

  f16* ep = smem;
  if (which < 2) {
    // ---- Q/K: two row-half passes through LDS [128][264] ----
    f16* QK = which == 0 ? Qo : Ko;
#pragma unroll 1
    for (int p = 0; p < 2; ++p) {
      __syncthreads();
      if (wm == p) {
#pragma unroll
        for (int ii = 0; ii < 8; ++ii)
#pragma unroll
          for (int j = 0; j < 4; ++j)
#pragma unroll
            for (int r = 0; r < 4; ++r)
              ep[((ii >> 2) * 64 + (ii & 3) * 16 + g16 * 4 + r) * 264 + wn * 64 + j * 16 + c]
                  = (f16)(acc[ii][j][r] + bb[j]);
      }
      __syncthreads();
      const int row = threadIdx.x >> 2, seg = (threadIdx.x & 3) * 64;
      f16* dst = QK + (size_t)(brow0 + p * 128 + row) * 768 + colhdr + seg;
      const f16* sp = ep + row * 264 + seg;
#pragma unroll
      for (int u = 0; u < 4; ++u) *(half8*)(dst + u * 8) = *(const half8*)(sp + u * 8);
#pragma unroll
      for (int u = 4; u < 8; ++u) *(half8*)(dst + u * 8) = *(const half8*)(sp + u * 8);
    }
  } else {
    // ---- V: two col-half passes, transposed LDS [128 col][264] -> VT ----
    const int bIdx = brow0 >> 12;
#pragma unroll 1
    for (int ch = 0; ch < 2; ++ch) {
      __syncthreads();
      if ((wn >> 1) == ch) {
        const int cih0 = (wn & 1) * 64;
#pragma unroll
        for (int ii = 0; ii < 8; ++ii)
#pragma unroll
          for (int j = 0; j < 4; ++j)
#pragma unroll
            for (int r = 0; r < 4; ++r)
              ep[(cih0 + j * 16 + c) * 264 + wm * 128 + (ii >> 2) * 64 + (ii & 3) * 16 + g16 * 4 + r]
                  = (f16)(acc[ii][j][r] + bb[j]);
      }
      __syncthreads();
      const int cl = threadIdx.x >> 2, seg = (threadIdx.x & 3) * 64;
      const int vcol = colhdr + ch * 128 + cl;
      const int h = vcol >> 6, d = vcol & 63;
      f16* dst = VT + ((size_t)(bIdx * 12 + h) * 64 + d) * 4096 + (brow0 & 4095) + seg;
      const f16* sp = ep + cl * 264 + seg;
#pragma unroll
      for (int u = 0; u < 8; ++u) *(half8*)(dst + u * 8) = *(const half8*)(sp + u * 8);
    }
  }
}

// ---------------- final GEMM ----------------
__global__ __launch_bounds__(512, 2) void k_gemm_out4(const f16* __restrict__ ATT, const f16* __restrict__ WOT,
    const float* __restrict__ bo, float* __restrict__ out)
{
  __shared__ f16 smem[65536];
  f32x4 acc[8][4];
  // 192 = 8 xcd * (8 bx * 3 by)
  const int lin = blockIdx.x;
  const int xcd = lin & 7, idx = lin >> 3;
  const int bx = xcd * 8 + idx / 3;      // [0,64)
  const int by = idx % 3;                // [0,3)
  const int brow0 = bx * 256;
  const int t = threadIdx.x, w = t >> 6, lane = t & 63;
  gemm8p_core(ATT + (size_t)brow0 * 768, WOT + (size_t)by * 256 * 768, smem, acc, w, lane);

  const int wm = w >> 2, wn = w & 3;
  const int c = lane & 15, g16 = lane >> 4;
  float bb[4];
#pragma unroll
  for (int j = 0; j < 4; ++j) bb[j] = bo[by * 256 + wn * 64 + j * 16 + c];
#pragma unroll
  for (int ii = 0; ii < 8; ++ii) {
    const int row0 = brow0 + wm * 128 + (ii >> 2) * 64 + (ii & 3) * 16 + g16 * 4;
#pragma unroll
    for (int j = 0; j < 4; ++j) {
      const int col = by * 256 + wn * 64 + j * 16 + c;
#pragma unroll
      for (int r = 0; r < 4; ++r)
        out[(size_t)(row0 + r) * 768 + col] = acc[ii][j][r] + bb[j];
    }
  }
}

// =====================================================================
// 128-tile GEMM core (kept for kvs / num kernels)
// =====================================================================
template<int BN>
DEVINL void gemm_tile(const f16* A, int lda, const f16* Bt, int ldb, int K,
                      f16* As, f16* Bs, f32x4 (&acc)[4][BN/32])
{
  constexpr int NF = BN/32;
  const int t = threadIdx.x;
  const int w = t >> 6, lane = t & 63;
  const int g = lane >> 4, c = lane & 15;
  const int wr = w >> 1, wc = w & 1;
  const int srow = lane >> 2;
  const int sseg = (lane & 3) * 8;

#pragma unroll
  for (int i = 0; i < 4; ++i)
#pragma unroll
    for (int j = 0; j < NF; ++j)
      acc[i][j] = f32x4{0.f, 0.f, 0.f, 0.f};

  for (int k0 = 0; k0 < K; k0 += 32) {
#pragma unroll
    for (int r = 0; r < 2; ++r) {                 // A: 128 rows x 64B
      const int rowblk = (w + 4*r) * 16;
      gload_lds16(A + (size_t)(rowblk + srow) * lda + k0 + sseg, As + rowblk*32);
    }
#pragma unroll
    for (int r = 0; r < BN/64; ++r) {             // B: BN rows x 64B
      const int rowblk = (w + 4*r) * 16;
      gload_lds16(Bt + (size_t)(rowblk + srow) * ldb + k0 + sseg, Bs + rowblk*32);
    }
    __syncthreads();
    half8 av[4], bv[NF];
#pragma unroll
    for (int i = 0; i < 4; ++i)
      av[i] = *(const half8*)(As + (wr*64 + i*16 + c)*32 + g*8);
#pragma unroll
    for (int j = 0; j < NF; ++j)
      bv[j] = *(const half8*)(Bs + (wc*(BN/2) + j*16 + c)*32 + g*8);
#pragma unroll
    for (int i = 0; i < 4; ++i)
#pragma unroll
      for (int j = 0; j < NF; ++j)
        acc[i][j] = __builtin_amdgcn_mfma_f32_16x16x32_f16(av[i], bv[j], acc[i][j], 0, 0, 0);
    __syncthreads();
  }
}

// ---------------- cast / transpose kernels ----------------
__global__ __launch_bounds__(256) void k_cast_x(const float* __restrict__ X, f16* __restrict__ X16)
{
  const size_t i = ((size_t)blockIdx.x*256 + threadIdx.x) * 4;
  const float4 v = *(const float4*)(X + i);
  half4 h;
  h[0] = (f16)v.x; h[1] = (f16)v.y; h[2] = (f16)v.z; h[3] = (f16)v.w;
  *(half4*)(X16 + i) = h;
}

__global__ __launch_bounds__(256) void k_transpose_w(const float* __restrict__ W, f16* __restrict__ Wt)
{
  __shared__ float ls[64][65];
  const int t = threadIdx.x;
  const int k0 = blockIdx.x*64, n0 = blockIdx.y*64;
#pragma unroll
  for (int it = 0; it < 4; ++it) {
    const int r = it*16 + (t >> 4);
    const int cs = (t & 15) * 4;
    const float4 v = *(const float4*)(W + (size_t)(k0 + r)*768 + n0 + cs);
    ls[r][cs+0] = v.x; ls[r][cs+1] = v.y; ls[r][cs+2] = v.z; ls[r][cs+3] = v.w;
  }
  __syncthreads();
  const int n = t >> 2;
  const int seg = (t & 3) * 16;
  half8 ov[2];
#pragma unroll
  for (int i = 0; i < 16; ++i) ov[i>>3][i&7] = (f16)ls[seg + i][n];
  f16* dst = Wt + (size_t)(n0 + n)*768 + k0 + seg;
  *(half8*)dst = ov[0];
  *(half8*)(dst + 8) = ov[1];
}

__global__ __launch_bounds__(256) void k_cast_proj(const float* __restrict__ P, f16* __restrict__ PF)
{
  const int i = blockIdx.x*256 + threadIdx.x;   // 8192
  PF[i] = (f16)(NORMALIZER * P[i]);
}

// ---------------- feature kernels ----------------
DEVINL void feat_common(const f16* base, const f16* PROJF,
                        f16* qs, f16* ps, float* dd, float* diag_s)
{
  const int t = threadIdx.x, w = t >> 6, lane = t & 63;
#pragma unroll
  for (int it = 0; it < 2; ++it) {
    const int rowblk = it*32 + w*8;
    gload_lds16(base + (size_t)(rowblk + (lane>>3))*768 + (lane&7)*8, qs + rowblk*64);
  }
#pragma unroll
  for (int it = 0; it < 4; ++it) {
    const int rowblk = it*32 + w*8;
    gload_lds16(PROJF + (size_t)(rowblk + (lane>>3))*64 + (lane&7)*8, ps + rowblk*64);
  }
  __syncthreads();
  if (t < 64) {
    float s = 0.f;
    for (int d = 0; d < 64; ++d) { const float qv = (float)qs[t*64 + d]; s += qv*qv; }
    diag_s[t] = 0.0625f * s;   // 0.5 * (normalizer^2) * sum q^2
  }
  const int g = lane >> 4, c = lane & 15;
  const int wr = w >> 1, wc = w & 1;
  f32x4 facc[2][4];
#pragma unroll
  for (int i = 0; i < 2; ++i)
#pragma unroll
    for (int j = 0; j < 4; ++j) facc[i][j] = f32x4{0.f,0.f,0.f,0.f};
#pragma unroll
  for (int kk = 0; kk < 2; ++kk) {
    half8 av[2], bv[4];
#pragma unroll
    for (int i = 0; i < 2; ++i) av[i] = *(const half8*)(qs + (wr*32 + i*16 + c)*64 + kk*32 + g*8);
#pragma unroll
    for (int j = 0; j < 4; ++j) bv[j] = *(const half8*)(ps + (wc*64 + j*16 + c)*64 + kk*32 + g*8);
#pragma unroll
    for (int i = 0; i < 2; ++i)
#pragma unroll
      for (int j = 0; j < 4; ++j)
        facc[i][j] = __builtin_amdgcn_mfma_f32_16x16x32_f16(av[i], bv[j], facc[i][j], 0, 0, 0);
  }
#pragma unroll
  for (int i = 0; i < 2; ++i)
#pragma unroll
    for (int j = 0; j < 4; ++j)
#pragma unroll
      for (int r = 0; r < 4; ++r)
        dd[(wr*32 + i*16 + g*4 + r)*129 + wc*64 + j*16 + c] = facc[i][j][r];
  __syncthreads();
}

__global__ __launch_bounds__(256) void k_qfeat(const f16* __restrict__ Q, const f16* __restrict__ PROJF,
    const float* __restrict__ KS, f16* __restrict__ QP, float* __restrict__ DEN)
{
  __shared__ f16 qs[64*64];
  __shared__ f16 ps[128*64];
  __shared__ float dd[64*129];
  __shared__ float diag_s[64];
  __shared__ float ks_s[128];
  const int t = threadIdx.x;
  const int lb = blockIdx.x, bh = blockIdx.y;
  const int b = bh / 12, h = bh - b*12;
  if (t < 128) ks_s[t] = KS[bh*128 + t];
  feat_common(Q + ((size_t)(b*4096 + lb*64))*768 + h*64, PROJF, qs, ps, dd, diag_s);
  const int l = t >> 2, s = t & 3;
  float v[32];
#pragma unroll
  for (int j = 0; j < 32; ++j) v[j] = dd[l*129 + s*32 + j];
  float mx = v[0];
#pragma unroll
  for (int j = 1; j < 32; ++j) mx = fmaxf(mx, v[j]);
  mx = fmaxf(mx, __shfl_xor(mx, 1));
  mx = fmaxf(mx, __shfl_xor(mx, 2));
  const float off = diag_s[l] + mx;
  half8 ov[4];
  float dp = 0.f;
#pragma unroll
  for (int j = 0; j < 32; ++j) {
    const float e = RATIO * (__expf(v[j] - off) + FEPS);
    ov[j>>3][j&7] = (f16)e;
    dp += e * ks_s[s*32 + j];
  }
  dp += __shfl_xor(dp, 1);
  dp += __shfl_xor(dp, 2);
  const size_t lrow = (size_t)bh*4096 + lb*64 + l;
  if (s == 0) DEN[lrow] = dp;
  f16* dst = QP + lrow*128 + s*32;
#pragma unroll
  for (int q8 = 0; q8 < 4; ++q8) *(half8*)(dst + q8*8) = ov[q8];
}

__global__ __launch_bounds__(256) void k_kfeat(const f16* __restrict__ Kin, const f16* __restrict__ PROJF,
    f16* __restrict__ KPT, float* __restrict__ KSP)
{
  __shared__ f16 qs[64*64];
  __shared__ f16 ps[128*64];
  __shared__ float dd[64*129];
  __shared__ float diag_s[64];
  const int t = threadIdx.x;
  const int lb = blockIdx.x, bh = blockIdx.y;
  const int b = bh / 12, h = bh - b*12;
  feat_common(Kin + ((size_t)(b*4096 + lb*64))*768 + h*64, PROJF, qs, ps, dd, diag_s);
  const int l = t >> 2, s = t & 3;
  float v[32];
#pragma unroll
  for (int j = 0; j < 32; ++j) v[j] = dd[l*129 + s*32 + j];
  float mx = v[0];
#pragma unroll
  for (int j = 1; j < 32; ++j) mx = fmaxf(mx, v[j]);
  mx = fmaxf(mx, __shfl_xor(mx, 1));
  mx = fmaxf(mx, __shfl_xor(mx, 2));
  const float off = diag_s[l] + mx;
#pragma unroll
  for (int j = 0; j < 32; ++j) dd[l*129 + s*32 + j] = RATIO * (__expf(v[j] - off) + FEPS);
  __syncthreads();
  if (t < 128) {
    float sm = 0.f;
    for (int l2 = 0; l2 < 64; ++l2) sm += dd[l2*129 + t];
    KSP[((size_t)bh*64 + lb)*128 + t] = sm;
  }
  const int m = t >> 1, hf = t & 1;
  half8 ov[4];
#pragma unroll
  for (int i2 = 0; i2 < 32; ++i2) ov[i2>>3][i2&7] = (f16)dd[(hf*32 + i2)*129 + m];
  f16* dst = KPT + ((size_t)bh*128 + m)*4096 + lb*64 + hf*32;
#pragma unroll
  for (int q8 = 0; q8 < 4; ++q8) *(half8*)(dst + q8*8) = ov[q8];
}

// ---------------- kvs: [48] (128m x 64d) = k'^T @ v, chunked over L ----------------
__global__ __launch_bounds__(256) void k_kvs(const f16* __restrict__ KPT, const f16* __restrict__ VT,
    float* __restrict__ KVSP)
{
  __shared__ f16 As[128*32], Bs[64*32];
  f32x4 acc[4][2];
  const int chunk = blockIdx.x, bh = blockIdx.y;   // (8, 48)
  gemm_tile<64>(KPT + (size_t)bh*128*4096 + chunk*512, 4096,
                VT  + (size_t)bh*64*4096  + chunk*512, 4096, 512, As, Bs, acc);
  const int t = threadIdx.x, w = t>>6, lane = t&63, g = lane>>4, c = lane&15;
  const int wr = w>>1, wc = w&1;
  float* dst = KVSP + (size_t)(chunk*48 + bh)*128*64;
#pragma unroll
  for (int i = 0; i < 4; ++i) {
    const int row0 = wr*64 + i*16 + g*4;
#pragma unroll
    for (int j = 0; j < 2; ++j) {
      const int col = wc*32 + j*16 + c;
#pragma unroll
      for (int r = 0; r < 4; ++r) dst[(size_t)(row0 + r)*64 + col] = acc[i][j][r];
    }
  }
}

__global__ __launch_bounds__(256) void k_reduce(const float* __restrict__ KVSP, const float* __restrict__ KSP,
    f16* __restrict__ KVST, float* __restrict__ KS)
{
  const int i = blockIdx.x*256 + threadIdx.x;
  if (i < 48*128*64) {
    const int bh = i >> 13, md = i & 8191, m = md >> 6, d = md & 63;
    float s = 0.f;
#pragma unroll
    for (int c = 0; c < 8; ++c) s += KVSP[((size_t)(c*48 + bh)*128 + m)*64 + d];
    KVST[((size_t)bh*64 + d)*128 + m] = (f16)s;
  }
  if (i < 48*128) {
    const int bh = i >> 7, m = i & 127;
    float s = 0.f;
#pragma unroll 8
    for (int lb = 0; lb < 64; ++lb) s += KSP[((size_t)bh*64 + lb)*128 + m];
    KS[i] = s;
  }
}

// ---------------- num GEMM + normalize -> ATT [bh][l][d] f16 ----------------
__global__ __launch_bounds__(256) void k_num(const f16* __restrict__ QP, const f16* __restrict__ KVST,
    const float* __restrict__ DEN, f16* __restrict__ ATT)
{
  __shared__ f16 As[128*32], Bs[64*32];
  f32x4 acc[4][2];
  const int bx = blockIdx.x, bh = blockIdx.y;      // (32, 48)
  gemm_tile<64>(QP + ((size_t)bh*4096 + bx*128)*128, 128,
                KVST + (size_t)bh*64*128, 128, 128, As, Bs, acc);
  const int t = threadIdx.x, w = t>>6, lane = t&63, g = lane>>4, c = lane&15;
  const int wr = w>>1, wc = w&1;
#pragma unroll
  for (int i = 0; i < 4; ++i) {
    const int l0 = bx*128 + wr*64 + i*16 + g*4;
#pragma unroll
    for (int j = 0; j < 2; ++j) {
      const int d = wc*32 + j*16 + c;
#pragma unroll
      for (int r = 0; r < 4; ++r) {
        const float den = DEN[(size_t)bh*4096 + l0 + r];
        ATT[((size_t)bh*4096 + l0 + r)*64 + d] = (f16)(acc[i][j][r] / den);
      }
    }
  }
}

// ---------------- launcher ----------------
extern "C" void kernel_launch(void* const* d_in, const int* in_sizes, int n_in,
                              void* d_out, int out_size, void* d_ws, size_t ws_size,
                              hipStream_t stream)
{
  const float* x    = (const float*)d_in[0];
  const float* Wq   = (const float*)d_in[1];
  const float* bq   = (const float*)d_in[2];
  const float* Wk   = (const float*)d_in[3];
  const float* bk   = (const float*)d_in[4];
  const float* Wv   = (const float*)d_in[5];
  const float* bv   = (const float*)d_in[6];
  const float* Wo   = (const float*)d_in[7];
  const float* bo   = (const float*)d_in[8];
  const float* proj = (const float*)d_in[9];
  float* out = (float*)d_out;
  char* ws = (char*)d_ws;

  f16*   WQKVT = (f16*)(ws + OFF_WQKVT);
  f16*   WOT   = (f16*)(ws + OFF_WOT);
  f16*   PROJF = (f16*)(ws + OFF_PROJF);
  float* KS    = (float*)(ws + OFF_KS);
  float* KSP   = (float*)(ws + OFF_KSP);
  float* DEN   = (float*)(ws + OFF_DEN);
  f16*   KVST  = (f16*)(ws + OFF_KVST);
  float* KVSP  = (float*)(ws + OFF_KVSP);
  f16*   X16   = (f16*)(ws + OFF_X16);
  f16*   ATT   = (f16*)(ws + OFF_ATT);
  f16*   Q16   = (f16*)(ws + OFF_Q16);
  f16*   K16   = (f16*)(ws + OFF_K16);
  f16*   VT    = (f16*)(ws + OFF_VT);
  f16*   QP    = (f16*)(ws + OFF_QP);
  f16*   KPT   = (f16*)(ws + OFF_KPT);

  k_cast_x<<<12288, 256, 0, stream>>>(x, X16);
  k_transpose_w<<<dim3(12,12), 256, 0, stream>>>(Wq, WQKVT);
  k_transpose_w<<<dim3(12,12), 256, 0, stream>>>(Wk, WQKVT + (size_t)768*768);
  k_transpose_w<<<dim3(12,12), 256, 0, stream>>>(Wv, WQKVT + (size_t)2*768*768);
  k_transpose_w<<<dim3(12,12), 256, 0, stream>>>(Wo, WOT);
  k_cast_proj<<<32, 256, 0, stream>>>(proj, PROJF);

  k_gemm_qkv4<<<576, 512, 0, stream>>>(X16, WQKVT, bq, bk, bv, Q16, K16, VT);
  k_kfeat<<<dim3(64,48), 256, 0, stream>>>(K16, PROJF, KPT, KSP);
  k_kvs<<<dim3(8,48), 256, 0, stream>>>(KPT, VT, KVSP);
  k_reduce<<<1536, 256, 0, stream>>>(KVSP, KSP, KVST, KS);
  k_qfeat<<<dim3(64,48), 256, 0, stream>>>(Q16, PROJF, KS, QP, DEN);
  k_num<<<dim3(32,48), 256, 0, stream>>>(QP, KVST, DEN, ATT);
  k_gemm_out4<<<192, 512, 0, stream>>>(ATT, WOT, bo, out);
}

// Round 5
// 251.496 us; speedup vs baseline: 1.2174x; 1.1271x over previous
//
#include <hip/hip_runtime.h>

typedef _Float16 f16;
typedef __attribute__((ext_vector_type(8))) _Float16 half8;
typedef __attribute__((ext_vector_type(4))) _Float16 half4;
typedef __attribute__((ext_vector_type(4))) float f32x4;

#define DEVINL static __device__ __forceinline__

constexpr float NORMALIZER = 0.35355339059327373f;  // 64^-0.25
constexpr float RATIO      = 0.08838834764831845f;  // 1/sqrt(128)
constexpr float FEPS       = 1e-6f;

// ---------------- workspace layout (bytes) ----------------
constexpr size_t OFF_WQKVT = 0;                                   // [2304][768] f16
constexpr size_t OFF_WOT   = OFF_WQKVT + (size_t)2304*768*2;      // [768][768] f16
constexpr size_t OFF_PROJF = OFF_WOT   + (size_t)768*768*2;       // [128][64] f16 (pre-scaled)
constexpr size_t OFF_KS    = OFF_PROJF + (size_t)128*64*2;        // [48][128] f32
constexpr size_t OFF_KSP   = OFF_KS    + (size_t)48*128*4;        // [48*64][128] f32
constexpr size_t OFF_DEN   = OFF_KSP   + (size_t)48*64*128*4;     // [48][4096] f32 (unused now)
constexpr size_t OFF_KVST  = OFF_DEN   + (size_t)48*4096*4;       // [48][64][128] f16
constexpr size_t OFF_KVSP  = OFF_KVST  + (size_t)48*64*128*2;     // [8][48][128][64] f32
constexpr size_t OFF_X16   = OFF_KVSP  + (size_t)8*48*128*64*4;   // [16384][768] f16
constexpr size_t OFF_ATT   = OFF_X16;                              // alias (x16 dead after QKV GEMM)
constexpr size_t OFF_Q16   = OFF_X16 + (size_t)16384*768*2;
constexpr size_t OFF_K16   = OFF_Q16 + (size_t)16384*768*2;
constexpr size_t OFF_VT    = OFF_K16 + (size_t)16384*768*2;       // [48][64][4096] f16
constexpr size_t OFF_KPT   = OFF_VT  + (size_t)16384*768*2;       // [48][128][4096] f16

// ---------------- helpers ----------------
DEVINL void gload_lds16(const f16* g, f16* lds) {
  __builtin_amdgcn_global_load_lds(
      (const __attribute__((address_space(1))) void*)g,
      (__attribute__((address_space(3))) void*)lds, 16, 0, 0);
}

#define VMCNT(n)  asm volatile("s_waitcnt vmcnt(" #n ")" ::: "memory")
#define LGKMCNT0  asm volatile("s_waitcnt lgkmcnt(0)" ::: "memory")
#define SCHEDB    __builtin_amdgcn_sched_barrier(0)
#define BAR       __builtin_amdgcn_s_barrier()

// =====================================================================
// 256x192 8-phase GEMM core, f16 in / f32 acc.  C = A[256xK] * Bt[192xK]^T
// (lda=ldb=768, K=768).  512 thr = 8 waves (2M x 4N); wave tile 128x48.
// LDS per buffer (f16): A kh0 [256][32] @0, A kh1 @8192, B [192][64] @16384
// -> 28672 f16 = 56 KiB; double-buffered = 112 KiB.
// Swizzles (both-sides): A (64B rows): seg' = seg ^ ((r>>1)&3)  [quad-bijective]
//                        B (128B rows): seg' = seg ^ (r&7)
// Staging per tile (uniform per wave): SA0(2 loads/thr), SB(3), SA1(2).
// Waits: P2-end vmcnt(5), P4-end vmcnt(2) — never 0 in steady state.
// =====================================================================
DEVINL void gemm192_core(const f16* __restrict__ Ag, const f16* __restrict__ Bg,
                         f16* smem, f32x4 (&acc)[8][3], int w, int lane)
{
  constexpr int NT = 12;                 // 768 / 64
  const int wm = w >> 2, wn = w & 3;
  const int c = lane & 15, g16 = lane >> 4;
  const int tid = threadIdx.x;

#pragma unroll
  for (int i = 0; i < 8; ++i)
#pragma unroll
    for (int j = 0; j < 3; ++j)
      acc[i][j] = f32x4{0.f, 0.f, 0.f, 0.f};

  auto SA = [&](int tt, int kh, f16* buf) {      // A k-half: 1024 x 16B
    f16* dst = buf + kh * 8192;
#pragma unroll
    for (int u = 0; u < 2; ++u) {
      const int id = u * 512 + tid;
      const int r = id >> 2, sg = id & 3;
      const int seg = sg ^ ((r >> 1) & 3);
      gload_lds16(Ag + (size_t)r * 768 + tt * 64 + kh * 32 + seg * 8,
                  dst + (u * 512 + w * 64) * 8);
    }
  };
  auto SB = [&](int tt, f16* buf) {              // B full tile: 1536 x 16B
    f16* dst = buf + 16384;
#pragma unroll
    for (int u = 0; u < 3; ++u) {
      const int id = u * 512 + tid;
      const int r = id >> 3, sg = id & 7;
      const int seg = sg ^ (r & 7);
      gload_lds16(Bg + (size_t)r * 768 + tt * 64 + seg * 8,
                  dst + (u * 512 + w * 64) * 8);
    }
  };
  auto RDA = [&](const f16* buf, int kh, int mh, half8 (&av)[4]) {
    const f16* base = buf + kh * 8192;
#pragma unroll
    for (int i = 0; i < 4; ++i) {
      const int r = wm * 128 + mh * 64 + i * 16 + c;
      av[i] = *(const half8*)(base + r * 32 + ((g16 ^ ((r >> 1) & 3)) << 3));
    }
  };
  auto RDB = [&](const f16* buf, int kh, half8 (&bv)[3]) {
#pragma unroll
    for (int j = 0; j < 3; ++j) {
      const int r = wn * 48 + j * 16 + c;
      const int s = kh * 4 + g16;
      bv[j] = *(const half8*)(buf + 16384 + r * 64 + ((s ^ (r & 7)) << 3));
    }
  };

  // -------- prologue: stage tile 0 (7 loads/thread) --------
  SA(0, 0, smem); SB(0, smem); SA(0, 1, smem);
  VMCNT(0);
  BAR; SCHEDB;

#pragma unroll 1
  for (int t = 0; t < NT; ++t) {
    f16* bufR = smem + (t & 1) * 28672;
    f16* bufW = smem + ((t & 1) ^ 1) * 28672;
    const bool st = (t + 1) < NT;
    half8 av[4], bv[3];

    // ---- P1: kh0, mh0 ----
    RDA(bufR, 0, 0, av); RDB(bufR, 0, bv);
    if (st) SA(t + 1, 0, bufW);
    SCHEDB; BAR; LGKMCNT0; SCHEDB;
    __builtin_amdgcn_s_setprio(1);
#pragma unroll
    for (int i = 0; i < 4; ++i)
#pragma unroll
      for (int j = 0; j < 3; ++j)
        acc[i][j] = __builtin_amdgcn_mfma_f32_16x16x32_f16(av[i], bv[j], acc[i][j], 0, 0, 0);
    __builtin_amdgcn_s_setprio(0);
    BAR; SCHEDB;
    // ---- P2: kh0, mh1 ----
    RDA(bufR, 0, 1, av);
    if (st) SB(t + 1, bufW);
    SCHEDB; BAR; LGKMCNT0; SCHEDB;
    __builtin_amdgcn_s_setprio(1);
#pragma unroll
    for (int i = 0; i < 4; ++i)
#pragma unroll
      for (int j = 0; j < 3; ++j)
        acc[4 + i][j] = __builtin_amdgcn_mfma_f32_16x16x32_f16(av[i], bv[j], acc[4 + i][j], 0, 0, 0);
    __builtin_amdgcn_s_setprio(0);
    if (st) { VMCNT(5); } else { VMCNT(0); }
    BAR; SCHEDB;
    // ---- P3: kh1, mh0 ----
    RDA(bufR, 1, 0, av); RDB(bufR, 1, bv);
    if (st) SA(t + 1, 1, bufW);
    SCHEDB; BAR; LGKMCNT0; SCHEDB;
    __builtin_amdgcn_s_setprio(1);
#pragma unroll
    for (int i = 0; i < 4; ++i)
#pragma unroll
      for (int j = 0; j < 3; ++j)
        acc[i][j] = __builtin_amdgcn_mfma_f32_16x16x32_f16(av[i], bv[j], acc[i][j], 0, 0, 0);
    __builtin_amdgcn_s_setprio(0);
    BAR; SCHEDB;
    // ---- P4: kh1, mh1 ----
    RDA(bufR, 1, 1, av);
    SCHEDB; BAR; LGKMCNT0; SCHEDB;
    __builtin_amdgcn_s_setprio(1);
#pragma unroll
    for (int i = 0; i < 4; ++i)
#pragma unroll
      for (int j = 0; j < 3; ++j)
        acc[4 + i][j] = __builtin_amdgcn_mfma_f32_16x16x32_f16(av[i], bv[j], acc[4 + i][j], 0, 0, 0);
    __builtin_amdgcn_s_setprio(0);
    if (st) { VMCNT(2); }
    BAR; SCHEDB;
  }
}

// ---------------- QKV GEMM (writes Q,K normal; V transposed) ----------------
__global__ __launch_bounds__(512, 2) void k_gemm_qkv5(const f16* __restrict__ X16, const f16* __restrict__ WT,
    const float* __restrict__ bq, const float* __restrict__ bk, const float* __restrict__ bv,
    f16* __restrict__ Qo, f16* __restrict__ Ko, f16* __restrict__ VT)
{
  __shared__ f16 smem[57344];            // 112 KiB
  f32x4 acc[8][3];
  // 768 blocks = 8 xcd * 96; same-bx panels grouped per XCD
  const int lin = blockIdx.x;
  const int xcd = lin & 7, chunk = lin >> 3;      // [0,96)
  const int bx = xcd * 8 + chunk / 12;            // [0,64)
  const int by = chunk % 12;                      // [0,12)
  const int brow0 = bx * 256;
  const int t = threadIdx.x, w = t >> 6, lane = t & 63;
  gemm192_core(X16 + (size_t)brow0 * 768, WT + (size_t)by * 192 * 768, smem, acc, w, lane);

  const int wm = w >> 2, wn = w & 3;
  const int c = lane & 15, g16 = lane >> 4;
  const int which = by >> 2;             // 0:q 1:k 2:v
  const int colhdr = (by & 3) * 192;
  const float* bias = which == 0 ? bq : (which == 1 ? bk : bv);
  float bb[3];
#pragma unroll
  for (int j = 0; j < 3; ++j) bb[j] = bias[colhdr + wn * 48 + j * 16 + c];

  f16* ep = smem;
  if (which < 2) {
    // ---- Q/K: row-major bounce [128][200], two row-half passes ----
    f16* QK = which == 0 ? Qo : Ko;
#pragma unroll 1
    for (int p = 0; p < 2; ++p) {
      __syncthreads();
      if (wm == p) {
#pragma unroll
        for (int ii = 0; ii < 8; ++ii)
#pragma unroll
          for (int j = 0; j < 3; ++j)
#pragma unroll
            for (int r = 0; r < 4; ++r)
              ep[((ii >> 2) * 64 + (ii & 3) * 16 + g16 * 4 + r) * 200 + wn * 48 + j * 16 + c]
                  = (f16)(acc[ii][j][r] + bb[j]);
      }
      __syncthreads();
      const int row = t >> 2, sg = (t & 3) * 48;
      f16* dst = QK + (size_t)(brow0 + p * 128 + row) * 768 + colhdr + sg;
      const f16* sp = ep + row * 200 + sg;
#pragma unroll
      for (int u = 0; u < 6; ++u) *(half8*)(dst + u * 8) = *(const half8*)(sp + u * 8);
    }
  } else {
    // ---- V: transposed bounce [192 col][136], two row-half passes ----
    const int bIdx = brow0 >> 12;
#pragma unroll 1
    for (int p = 0; p < 2; ++p) {
      __syncthreads();
      if (wm == p) {
#pragma unroll
        for (int ii = 0; ii < 8; ++ii)
#pragma unroll
          for (int j = 0; j < 3; ++j)
#pragma unroll
            for (int r = 0; r < 4; ++r)
              ep[(wn * 48 + j * 16 + c) * 136 + (ii >> 2) * 64 + (ii & 3) * 16 + g16 * 4 + r]
                  = (f16)(acc[ii][j][r] + bb[j]);
      }
      __syncthreads();
      if (t < 384) {
        const int cl = t >> 1, sg = (t & 1) * 64;
        const int vcol = colhdr + cl;
        const int h = vcol >> 6, d = vcol & 63;
        f16* dst = VT + ((size_t)(bIdx * 12 + h) * 64 + d) * 4096 + (brow0 & 4095) + p * 128 + sg;
        const f16* sp = ep + cl * 136 + sg;
#pragma unroll
        for (int u = 0; u < 8; ++u) *(half8*)(dst + u * 8) = *(const half8*)(sp + u * 8);
      }
    }
  }
}

// ---------------- final GEMM ----------------
__global__ __launch_bounds__(512, 2) void k_gemm_out5(const f16* __restrict__ ATT, const f16* __restrict__ WOT,
    const float* __restrict__ bo, float* __restrict__ out)
{
  __shared__ f16 smem[57344];
  f32x4 acc[8][3];
  // 256 blocks = 8 xcd * 32
  const int lin = blockIdx.x;
  const int xcd = lin & 7, chunk = lin >> 3;      // [0,32)
  const int bx = xcd * 8 + (chunk >> 2);          // [0,64)
  const int by = chunk & 3;                       // [0,4)
  const int brow0 = bx * 256;
  const int t = threadIdx.x, w = t >> 6, lane = t & 63;
  gemm192_core(ATT + (size_t)brow0 * 768, WOT + (size_t)by * 192 * 768, smem, acc, w, lane);

  const int wm = w >> 2, wn = w & 3;
  const int c = lane & 15, g16 = lane >> 4;
  float bb[3];
#pragma unroll
  for (int j = 0; j < 3; ++j) bb[j] = bo[by * 192 + wn * 48 + j * 16 + c];
#pragma unroll
  for (int ii = 0; ii < 8; ++ii) {
    const int row0 = brow0 + wm * 128 + (ii >> 2) * 64 + (ii & 3) * 16 + g16 * 4;
#pragma unroll
    for (int j = 0; j < 3; ++j) {
      const int col = by * 192 + wn * 48 + j * 16 + c;
#pragma unroll
      for (int r = 0; r < 4; ++r)
        out[(size_t)(row0 + r) * 768 + col] = acc[ii][j][r] + bb[j];
    }
  }
}

// =====================================================================
// 128-tile GEMM core (kept for kvs)
// =====================================================================
template<int BN>
DEVINL void gemm_tile(const f16* A, int lda, const f16* Bt, int ldb, int K,
                      f16* As, f16* Bs, f32x4 (&acc)[4][BN/32])
{
  constexpr int NF = BN/32;
  const int t = threadIdx.x;
  const int w = t >> 6, lane = t & 63;
  const int g = lane >> 4, c = lane & 15;
  const int wr = w >> 1, wc = w & 1;
  const int srow = lane >> 2;
  const int sseg = (lane & 3) * 8;

#pragma unroll
  for (int i = 0; i < 4; ++i)
#pragma unroll
    for (int j = 0; j < NF; ++j)
      acc[i][j] = f32x4{0.f, 0.f, 0.f, 0.f};

  for (int k0 = 0; k0 < K; k0 += 32) {
#pragma unroll
    for (int r = 0; r < 2; ++r) {
      const int rowblk = (w + 4*r) * 16;
      gload_lds16(A + (size_t)(rowblk + srow) * lda + k0 + sseg, As + rowblk*32);
    }
#pragma unroll
    for (int r = 0; r < BN/64; ++r) {
      const int rowblk = (w + 4*r) * 16;
      gload_lds16(Bt + (size_t)(rowblk + srow) * ldb + k0 + sseg, Bs + rowblk*32);
    }
    __syncthreads();
    half8 av[4], bv[NF];
#pragma unroll
    for (int i = 0; i < 4; ++i)
      av[i] = *(const half8*)(As + (wr*64 + i*16 + c)*32 + g*8);
#pragma unroll
    for (int j = 0; j < NF; ++j)
      bv[j] = *(const half8*)(Bs + (wc*(BN/2) + j*16 + c)*32 + g*8);
#pragma unroll
    for (int i = 0; i < 4; ++i)
#pragma unroll
      for (int j = 0; j < NF; ++j)
        acc[i][j] = __builtin_amdgcn_mfma_f32_16x16x32_f16(av[i], bv[j], acc[i][j], 0, 0, 0);
    __syncthreads();
  }
}

// ---------------- cast / transpose kernels ----------------
__global__ __launch_bounds__(256) void k_cast_x(const float* __restrict__ X, f16* __restrict__ X16)
{
  const size_t i = ((size_t)blockIdx.x*256 + threadIdx.x) * 4;
  const float4 v = *(const float4*)(X + i);
  half4 h;
  h[0] = (f16)v.x; h[1] = (f16)v.y; h[2] = (f16)v.z; h[3] = (f16)v.w;
  *(half4*)(X16 + i) = h;
}

__global__ __launch_bounds__(256) void k_transpose_w(const float* __restrict__ W, f16* __restrict__ Wt)
{
  __shared__ float ls[64][65];
  const int t = threadIdx.x;
  const int k0 = blockIdx.x*64, n0 = blockIdx.y*64;
#pragma unroll
  for (int it = 0; it < 4; ++it) {
    const int r = it*16 + (t >> 4);
    const int cs = (t & 15) * 4;
    const float4 v = *(const float4*)(W + (size_t)(k0 + r)*768 + n0 + cs);
    ls[r][cs+0] = v.x; ls[r][cs+1] = v.y; ls[r][cs+2] = v.z; ls[r][cs+3] = v.w;
  }
  __syncthreads();
  const int n = t >> 2;
  const int seg = (t & 3) * 16;
  half8 ov[2];
#pragma unroll
  for (int i = 0; i < 16; ++i) ov[i>>3][i&7] = (f16)ls[seg + i][n];
  f16* dst = Wt + (size_t)(n0 + n)*768 + k0 + seg;
  *(half8*)dst = ov[0];
  *(half8*)(dst + 8) = ov[1];
}

__global__ __launch_bounds__(256) void k_cast_proj(const float* __restrict__ P, f16* __restrict__ PF)
{
  const int i = blockIdx.x*256 + threadIdx.x;   // 8192
  PF[i] = (f16)(NORMALIZER * P[i]);
}

// ---------------- feature kernels ----------------
DEVINL void feat_common(const f16* base, const f16* PROJF,
                        f16* qs, f16* ps, float* dd, float* diag_s)
{
  const int t = threadIdx.x, w = t >> 6, lane = t & 63;
#pragma unroll
  for (int it = 0; it < 2; ++it) {
    const int rowblk = it*32 + w*8;
    gload_lds16(base + (size_t)(rowblk + (lane>>3))*768 + (lane&7)*8, qs + rowblk*64);
  }
#pragma unroll
  for (int it = 0; it < 4; ++it) {
    const int rowblk = it*32 + w*8;
    gload_lds16(PROJF + (size_t)(rowblk + (lane>>3))*64 + (lane&7)*8, ps + rowblk*64);
  }
  __syncthreads();
  if (t < 64) {
    float s = 0.f;
    for (int d = 0; d < 64; ++d) { const float qv = (float)qs[t*64 + d]; s += qv*qv; }
    diag_s[t] = 0.0625f * s;   // 0.5 * (normalizer^2) * sum q^2
  }
  const int g = lane >> 4, c = lane & 15;
  const int wr = w >> 1, wc = w & 1;
  f32x4 facc[2][4];
#pragma unroll
  for (int i = 0; i < 2; ++i)
#pragma unroll
    for (int j = 0; j < 4; ++j) facc[i][j] = f32x4{0.f,0.f,0.f,0.f};
#pragma unroll
  for (int kk = 0; kk < 2; ++kk) {
    half8 av[2], bv[4];
#pragma unroll
    for (int i = 0; i < 2; ++i) av[i] = *(const half8*)(qs + (wr*32 + i*16 + c)*64 + kk*32 + g*8);
#pragma unroll
    for (int j = 0; j < 4; ++j) bv[j] = *(const half8*)(ps + (wc*64 + j*16 + c)*64 + kk*32 + g*8);
#pragma unroll
    for (int i = 0; i < 2; ++i)
#pragma unroll
      for (int j = 0; j < 4; ++j)
        facc[i][j] = __builtin_amdgcn_mfma_f32_16x16x32_f16(av[i], bv[j], facc[i][j], 0, 0, 0);
  }
#pragma unroll
  for (int i = 0; i < 2; ++i)
#pragma unroll
    for (int j = 0; j < 4; ++j)
#pragma unroll
      for (int r = 0; r < 4; ++r)
        dd[(wr*32 + i*16 + g*4 + r)*129 + wc*64 + j*16 + c] = facc[i][j][r];
  __syncthreads();
}

__global__ __launch_bounds__(256) void k_kfeat(const f16* __restrict__ Kin, const f16* __restrict__ PROJF,
    f16* __restrict__ KPT, float* __restrict__ KSP)
{
  __shared__ f16 qs[64*64];
  __shared__ f16 ps[128*64];
  __shared__ float dd[64*129];
  __shared__ float diag_s[64];
  const int t = threadIdx.x;
  const int lb = blockIdx.x, bh = blockIdx.y;
  const int b = bh / 12, h = bh - b*12;
  feat_common(Kin + ((size_t)(b*4096 + lb*64))*768 + h*64, PROJF, qs, ps, dd, diag_s);
  const int l = t >> 2, s = t & 3;
  float v[32];
#pragma unroll
  for (int j = 0; j < 32; ++j) v[j] = dd[l*129 + s*32 + j];
  float mx = v[0];
#pragma unroll
  for (int j = 1; j < 32; ++j) mx = fmaxf(mx, v[j]);
  mx = fmaxf(mx, __shfl_xor(mx, 1));
  mx = fmaxf(mx, __shfl_xor(mx, 2));
  const float off = diag_s[l] + mx;
#pragma unroll
  for (int j = 0; j < 32; ++j) dd[l*129 + s*32 + j] = RATIO * (__expf(v[j] - off) + FEPS);
  __syncthreads();
  if (t < 128) {
    float sm = 0.f;
    for (int l2 = 0; l2 < 64; ++l2) sm += dd[l2*129 + t];
    KSP[((size_t)bh*64 + lb)*128 + t] = sm;
  }
  const int m = t >> 1, hf = t & 1;
  half8 ov[4];
#pragma unroll
  for (int i2 = 0; i2 < 32; ++i2) ov[i2>>3][i2&7] = (f16)dd[(hf*32 + i2)*129 + m];
  f16* dst = KPT + ((size_t)bh*128 + m)*4096 + lb*64 + hf*32;
#pragma unroll
  for (int q8 = 0; q8 < 4; ++q8) *(half8*)(dst + q8*8) = ov[q8];
}

// ---------------- kvs: [48] (128m x 64d) = k'^T @ v, chunked over L ----------------
__global__ __launch_bounds__(256) void k_kvs(const f16* __restrict__ KPT, const f16* __restrict__ VT,
    float* __restrict__ KVSP)
{
  __shared__ f16 As[128*32], Bs[64*32];
  f32x4 acc[4][2];
  const int chunk = blockIdx.x, bh = blockIdx.y;   // (8, 48)
  gemm_tile<64>(KPT + (size_t)bh*128*4096 + chunk*512, 4096,
                VT  + (size_t)bh*64*4096  + chunk*512, 4096, 512, As, Bs, acc);
  const int t = threadIdx.x, w = t>>6, lane = t&63, g = lane>>4, c = lane&15;
  const int wr = w>>1, wc = w&1;
  float* dst = KVSP + (size_t)(chunk*48 + bh)*128*64;
#pragma unroll
  for (int i = 0; i < 4; ++i) {
    const int row0 = wr*64 + i*16 + g*4;
#pragma unroll
    for (int j = 0; j < 2; ++j) {
      const int col = wc*32 + j*16 + c;
#pragma unroll
      for (int r = 0; r < 4; ++r) dst[(size_t)(row0 + r)*64 + col] = acc[i][j][r];
    }
  }
}

__global__ __launch_bounds__(256) void k_reduce(const float* __restrict__ KVSP, const float* __restrict__ KSP,
    f16* __restrict__ KVST, float* __restrict__ KS)
{
  const int i = blockIdx.x*256 + threadIdx.x;
  if (i < 48*128*64) {
    const int bh = i >> 13, md = i & 8191, m = md >> 6, d = md & 63;
    float s = 0.f;
#pragma unroll
    for (int c = 0; c < 8; ++c) s += KVSP[((size_t)(c*48 + bh)*128 + m)*64 + d];
    KVST[((size_t)bh*64 + d)*128 + m] = (f16)s;
  }
  if (i < 48*128) {
    const int bh = i >> 7, m = i & 127;
    float s = 0.f;
#pragma unroll 8
    for (int lb = 0; lb < 64; ++lb) s += KSP[((size_t)bh*64 + lb)*128 + m];
    KS[i] = s;
  }
}

// ---------------- fused q-feature + num GEMM + normalize -> ATT ----------------
// block: (lb in L/64, bh in 48). q' kept in swizzled LDS; kvs B-frags in regs.
__global__ __launch_bounds__(256) void k_qfn(const f16* __restrict__ Q, const f16* __restrict__ PROJF,
    const float* __restrict__ KS, const f16* __restrict__ KVST, f16* __restrict__ ATT)
{
  __shared__ f16 qs[64*64];
  __shared__ f16 ps[128*64];
  __shared__ float dd[64*129];
  __shared__ float diag_s[64];
  __shared__ float den_s[64];
  __shared__ f16 qp[64*128];
  __shared__ float ks_s[128];
  const int t = threadIdx.x;
  const int lb = blockIdx.x, bh = blockIdx.y;
  const int b = bh / 12, h = bh - b*12;
  if (t < 128) ks_s[t] = KS[bh*128 + t];
  feat_common(Q + ((size_t)(b*4096 + lb*64))*768 + h*64, PROJF, qs, ps, dd, diag_s);

  // kvs fragments: global -> reg (KVST tiny & L2-hot); hidden under softmax VALU
  const int w = t >> 6, lane = t & 63, g16 = lane >> 4, c = lane & 15;
  const int wr = w >> 1, wc = w & 1;
  half8 bv2[2][4];
#pragma unroll
  for (int j = 0; j < 2; ++j) {
    const int d = wc*32 + j*16 + c;
#pragma unroll
    for (int kk = 0; kk < 4; ++kk)
      bv2[j][kk] = *(const half8*)(KVST + (size_t)bh*8192 + d*128 + kk*32 + g16*8);
  }

  // softmax-kernel transform; q' -> swizzled LDS; den via ks dot
  const int l = t >> 2, s = t & 3;
  float v[32];
#pragma unroll
  for (int j = 0; j < 32; ++j) v[j] = dd[l*129 + s*32 + j];
  float mx = v[0];
#pragma unroll
  for (int j = 1; j < 32; ++j) mx = fmaxf(mx, v[j]);
  mx = fmaxf(mx, __shfl_xor(mx, 1));
  mx = fmaxf(mx, __shfl_xor(mx, 2));
  const float off = diag_s[l] + mx;
  half8 ov[4];
  float dp = 0.f;
#pragma unroll
  for (int j = 0; j < 32; ++j) {
    const float e = RATIO * (__expf(v[j] - off) + FEPS);
    ov[j>>3][j&7] = (f16)e;
    dp += e * ks_s[s*32 + j];
  }
  dp += __shfl_xor(dp, 1);
  dp += __shfl_xor(dp, 2);
  if (s == 0) den_s[l] = dp;
#pragma unroll
  for (int k = 0; k < 4; ++k)
    *(half8*)(qp + l*128 + (((4*s + k) ^ (l & 7)) << 3)) = ov[k];
  __syncthreads();

  // num MFMA: C[64 l][64 d] = qp[64][128] @ kvs^T ; 4 waves 2Mx2N, K=128
  f32x4 acc2[2][2];
#pragma unroll
  for (int i = 0; i < 2; ++i)
#pragma unroll
    for (int j = 0; j < 2; ++j) acc2[i][j] = f32x4{0.f,0.f,0.f,0.f};
#pragma unroll
  for (int kk = 0; kk < 4; ++kk) {
    half8 av2[2];
#pragma unroll
    for (int i = 0; i < 2; ++i) {
      const int l2 = wr*32 + i*16 + c;
      av2[i] = *(const half8*)(qp + l2*128 + (((kk*4 + g16) ^ (l2 & 7)) << 3));
    }
#pragma unroll
    for (int i = 0; i < 2; ++i)
#pragma unroll
      for (int j = 0; j < 2; ++j)
        acc2[i][j] = __builtin_amdgcn_mfma_f32_16x16x32_f16(av2[i], bv2[j][kk], acc2[i][j], 0, 0, 0);
  }

  // normalize + coalesced store via LDS bounce (reuse ps)
  f16* ep = ps;   // [64][72]
#pragma unroll
  for (int i = 0; i < 2; ++i)
#pragma unroll
    for (int j = 0; j < 2; ++j)
#pragma unroll
      for (int r = 0; r < 4; ++r) {
        const int l3 = wr*32 + i*16 + g16*4 + r;
        ep[l3*72 + wc*32 + j*16 + c] = (f16)(acc2[i][j][r] / den_s[l3]);
      }
  __syncthreads();
  const int row = t >> 2, sg = (t & 3) * 16;
  f16* dst = ATT + ((size_t)bh*4096 + lb*64 + row)*64 + sg;
  const f16* sp = ep + row*72 + sg;
  *(half8*)dst = *(const half8*)sp;
  *(half8*)(dst + 8) = *(const half8*)(sp + 8);
}

// ---------------- launcher ----------------
extern "C" void kernel_launch(void* const* d_in, const int* in_sizes, int n_in,
                              void* d_out, int out_size, void* d_ws, size_t ws_size,
                              hipStream_t stream)
{
  const float* x    = (const float*)d_in[0];
  const float* Wq   = (const float*)d_in[1];
  const float* bq   = (const float*)d_in[2];
  const float* Wk   = (const float*)d_in[3];
  const float* bk   = (const float*)d_in[4];
  const float* Wv   = (const float*)d_in[5];
  const float* bv   = (const float*)d_in[6];
  const float* Wo   = (const float*)d_in[7];
  const float* bo   = (const float*)d_in[8];
  const float* proj = (const float*)d_in[9];
  float* out = (float*)d_out;
  char* ws = (char*)d_ws;

  f16*   WQKVT = (f16*)(ws + OFF_WQKVT);
  f16*   WOT   = (f16*)(ws + OFF_WOT);
  f16*   PROJF = (f16*)(ws + OFF_PROJF);
  float* KS    = (float*)(ws + OFF_KS);
  float* KSP   = (float*)(ws + OFF_KSP);
  f16*   KVST  = (f16*)(ws + OFF_KVST);
  float* KVSP  = (float*)(ws + OFF_KVSP);
  f16*   X16   = (f16*)(ws + OFF_X16);
  f16*   ATT   = (f16*)(ws + OFF_ATT);
  f16*   Q16   = (f16*)(ws + OFF_Q16);
  f16*   K16   = (f16*)(ws + OFF_K16);
  f16*   VT    = (f16*)(ws + OFF_VT);
  f16*   KPT   = (f16*)(ws + OFF_KPT);

  k_cast_x<<<12288, 256, 0, stream>>>(x, X16);
  k_transpose_w<<<dim3(12,12), 256, 0, stream>>>(Wq, WQKVT);
  k_transpose_w<<<dim3(12,12), 256, 0, stream>>>(Wk, WQKVT + (size_t)768*768);
  k_transpose_w<<<dim3(12,12), 256, 0, stream>>>(Wv, WQKVT + (size_t)2*768*768);
  k_transpose_w<<<dim3(12,12), 256, 0, stream>>>(Wo, WOT);
  k_cast_proj<<<32, 256, 0, stream>>>(proj, PROJF);

  k_gemm_qkv5<<<768, 512, 0, stream>>>(X16, WQKVT, bq, bk, bv, Q16, K16, VT);
  k_kfeat<<<dim3(64,48), 256, 0, stream>>>(K16, PROJF, KPT, KSP);
  k_kvs<<<dim3(8,48), 256, 0, stream>>>(KPT, VT, KVSP);
  k_reduce<<<1536, 256, 0, stream>>>(KVSP, KSP, KVST, KS);
  k_qfn<<<dim3(64,48), 256, 0, stream>>>(Q16, PROJF, KS, KVST, ATT);
  k_gemm_out5<<<256, 512, 0, stream>>>(ATT, WOT, bo, out);
}